// Round 1
// baseline (2680.804 us; speedup 1.0000x reference)
//
#include <hip/hip_runtime.h>
#include <hip/hip_bf16.h>

// Problem constants (B,L,D)=(4,2048,768), K=12, M=1, CK=4, H=64
#define B_       4
#define L_       2048
#define D_       768
#define K_       12
#define H_       64
#define CK_      4
#define DIM_MEM_ 768
#define DMK      780        // DIM_MEM + K
#define DST_     4608       // K * DSH
#define NT       (B_*L_)    // 8192 tokens
#define NSUM     1536       // 2*K*H  (summary width)
#define NACT     2304       // K*192  (y_act width)
#define NCHUNK   16
#define CHLEN    (L_/NCHUNK)  // 128
#define PSTRIDE  132          // per-chunk partials stride (128 ch + den + pad)

// ---------------------------------------------------------------------------
// Generic fp32 SIMT GEMM: C[M,N] = A[M,K] * B[K,N]
// 64x64 tile, BK=16, 256 threads, 4x4 micro-tile per thread.
// As stored [k][m] padded to 68 (2-way-max bank aliasing on transpose stores,
// free per m136), enabling float4 LDS reads for both A and B fragments.
// ---------------------------------------------------------------------------
__global__ __launch_bounds__(256)
void gemm_f32(const float* __restrict__ A, const float* __restrict__ Bm,
              float* __restrict__ Cm, int M, int N, int Kd,
              int lda, int ldb, int ldc)
{
    __shared__ float As[16][68];
    __shared__ float Bs[16][64];
    int tid = threadIdx.x;
    int tx = tid & 15, ty = tid >> 4;
    int m0 = blockIdx.y * 64, n0 = blockIdx.x * 64;

    float acc[4][4] = {{0.f,0.f,0.f,0.f},{0.f,0.f,0.f,0.f},
                       {0.f,0.f,0.f,0.f},{0.f,0.f,0.f,0.f}};

    int a_m  = tid >> 2;          // 0..63
    int a_k4 = (tid & 3) * 4;     // 0,4,8,12
    int b_n  = tid & 63;
    int b_k0 = (tid >> 6) * 4;    // 0,4,8,12
    bool nok = (n0 + b_n) < N;

    for (int k0 = 0; k0 < Kd; k0 += 16) {
        float4 av = *reinterpret_cast<const float4*>(
            &A[(size_t)(m0 + a_m) * lda + k0 + a_k4]);
        As[a_k4 + 0][a_m] = av.x;
        As[a_k4 + 1][a_m] = av.y;
        As[a_k4 + 2][a_m] = av.z;
        As[a_k4 + 3][a_m] = av.w;
        #pragma unroll
        for (int i = 0; i < 4; ++i) {
            float v = nok ? Bm[(size_t)(k0 + b_k0 + i) * ldb + n0 + b_n] : 0.f;
            Bs[b_k0 + i][b_n] = v;
        }
        __syncthreads();
        #pragma unroll
        for (int kk = 0; kk < 16; ++kk) {
            float4 a4 = *reinterpret_cast<const float4*>(&As[kk][ty * 4]);
            float4 b4 = *reinterpret_cast<const float4*>(&Bs[kk][tx * 4]);
            acc[0][0] += a4.x*b4.x; acc[0][1] += a4.x*b4.y; acc[0][2] += a4.x*b4.z; acc[0][3] += a4.x*b4.w;
            acc[1][0] += a4.y*b4.x; acc[1][1] += a4.y*b4.y; acc[1][2] += a4.y*b4.z; acc[1][3] += a4.y*b4.w;
            acc[2][0] += a4.z*b4.x; acc[2][1] += a4.z*b4.y; acc[2][2] += a4.z*b4.z; acc[2][3] += a4.z*b4.w;
            acc[3][0] += a4.w*b4.x; acc[3][1] += a4.w*b4.y; acc[3][2] += a4.w*b4.z; acc[3][3] += a4.w*b4.w;
        }
        __syncthreads();
    }

    if (n0 + 63 < N) {
        #pragma unroll
        for (int i = 0; i < 4; ++i) {
            float4 v = make_float4(acc[i][0], acc[i][1], acc[i][2], acc[i][3]);
            *reinterpret_cast<float4*>(
                &Cm[(size_t)(m0 + ty*4 + i) * ldc + n0 + tx*4]) = v;
        }
    } else {
        #pragma unroll
        for (int i = 0; i < 4; ++i)
            #pragma unroll
            for (int j = 0; j < 4; ++j)
                if (n0 + tx*4 + j < N)
                    Cm[(size_t)(m0 + ty*4 + i) * ldc + n0 + tx*4 + j] = acc[i][j];
    }
}

// ---------------------------------------------------------------------------
// Token-local: causal conv(CK=4) + SiLU + RMSNorm(H) + phase -> pw, re, im
// One block per token; tid -> (wave kg = tid>>6, h = tid&63); each thread
// owns k in {kg, kg+4, kg+8}. RMS reduction = 64-lane shuffle within wave.
// ---------------------------------------------------------------------------
__global__ __launch_bounds__(256)
void token_kernel(const float* __restrict__ zmem, const float* __restrict__ conv_w,
                  const float* __restrict__ rms_scale, const float* __restrict__ theta_raw,
                  const float* __restrict__ dslopes, const float* __restrict__ sscale,
                  const float* __restrict__ tscale,
                  float* __restrict__ pw, float* __restrict__ re, float* __restrict__ im)
{
    int t = blockIdx.x;
    int b = t >> 11;          // L = 2048
    int l = t & (L_ - 1);
    int tid = threadIdx.x;
    int h = tid & 63, kg = tid >> 6;

    __shared__ float s_pw[K_];

    if (tid < K_) {
        float acc = 0.f;
        #pragma unroll
        for (int j = 0; j < CK_; ++j) {
            int ll = l - (CK_ - 1) + j;
            if (ll >= 0)
                acc += zmem[(size_t)(b*L_ + ll)*DMK + DIM_MEM_ + tid]
                     * conv_w[j*DMK + DIM_MEM_ + tid];
        }
        float s  = acc / (1.f + expf(-acc));            // silu
        float lp = sscale[tid] * s;
        lp = fminf(10.f, fmaxf(-10.f, lp));
        float slope = log1pf(expf(dslopes[tid]));       // softplus
        s_pw[tid] = expf(lp - slope * (float)(L_ - 1 - l));
    }

    float kv[3];
    #pragma unroll
    for (int q = 0; q < 3; ++q) {
        int kk = kg + q*4;
        int c = kk*H_ + h;
        float acc = 0.f;
        #pragma unroll
        for (int j = 0; j < CK_; ++j) {
            int ll = l - (CK_ - 1) + j;
            if (ll >= 0)
                acc += zmem[(size_t)(b*L_ + ll)*DMK + c] * conv_w[j*DMK + c];
        }
        kv[q] = acc / (1.f + expf(-acc));               // silu
    }
    __syncthreads();

    #pragma unroll
    for (int q = 0; q < 3; ++q) {
        int kk = kg + q*4;
        float v = kv[q];
        float ss = v * v;
        #pragma unroll
        for (int off = 32; off > 0; off >>= 1)
            ss += __shfl_xor(ss, off, 64);
        float kn = v * rsqrtf(ss * (1.f/64.f) + 1e-6f) * rms_scale[h];
        float th = 0.001f + 2.999f * (1.f / (1.f + expf(-theta_raw[kk*H_ + h])));
        float phi = tanhf(kn * tscale[kk]) * th;
        float kvw = kn * s_pw[kk];
        re[(size_t)t*(K_*H_) + kk*H_ + h] = kvw * cosf(phi);
        im[(size_t)t*(K_*H_) + kk*H_ + h] = kvw * sinf(phi);
    }
    if (tid < K_) pw[(size_t)t*K_ + tid] = s_pw[tid];
}

// ---------------------------------------------------------------------------
// Chunked scan, pass 1: per-(b,k,chunk) channel sums -> partials
// block = 128 threads: tid&63 = h, tid>>6 selects re/im. Den (pw) accumulated
// redundantly (broadcast loads), written by tid 0.
// ---------------------------------------------------------------------------
__global__ __launch_bounds__(128)
void scan_sums(const float* __restrict__ pw, const float* __restrict__ re,
               const float* __restrict__ im, float* __restrict__ part)
{
    int blk = blockIdx.x;
    int chunk = blk & (NCHUNK - 1);
    int bk = blk >> 4;
    int k = bk % K_;
    int b = bk / K_;
    int tid = threadIdx.x;
    int h = tid & 63;
    const float* __restrict__ src = (tid >> 6) ? im : re;
    int l0 = chunk * CHLEN;

    size_t base  = ((size_t)(b*L_ + l0))*(K_*H_) + k*H_ + h;
    size_t dbase = ((size_t)(b*L_ + l0))*K_ + k;
    float s = 0.f, ds = 0.f;
    for (int i0 = 0; i0 < CHLEN; i0 += 8) {
        float v[8], d[8];
        #pragma unroll
        for (int j = 0; j < 8; ++j) {
            v[j] = src[base + (size_t)(i0 + j)*(K_*H_)];
            d[j] = pw [dbase + (size_t)(i0 + j)*K_];
        }
        #pragma unroll
        for (int j = 0; j < 8; ++j) { s += v[j]; ds += d[j]; }
    }
    size_t pb = ((size_t)bk * NCHUNK + chunk) * PSTRIDE;
    part[pb + tid] = s;
    if (tid == 0) part[pb + 128] = ds;
}

// ---------------------------------------------------------------------------
// Chunked scan, pass 2: offsets + sequential emit of summary (re/im * inv_den
// interleaved: summary[t][2*(k*H+h) + {0:re,1:im}]).
// ---------------------------------------------------------------------------
__global__ __launch_bounds__(128)
void scan_final(const float* __restrict__ pw, const float* __restrict__ re,
                const float* __restrict__ im, const float* __restrict__ part,
                float* __restrict__ summary)
{
    int blk = blockIdx.x;
    int chunk = blk & (NCHUNK - 1);
    int bk = blk >> 4;
    int k = bk % K_;
    int b = bk / K_;
    int tid = threadIdx.x;
    int h = tid & 63;
    int pi = tid >> 6;
    const float* __restrict__ src = pi ? im : re;
    int l0 = chunk * CHLEN;

    float acc = 0.f, dacc = 0.f;
    size_t pb0 = (size_t)bk * NCHUNK * PSTRIDE;
    for (int cn = 0; cn < chunk; ++cn) {
        acc  += part[pb0 + (size_t)cn*PSTRIDE + tid];
        dacc += part[pb0 + (size_t)cn*PSTRIDE + 128];
    }

    size_t base  = ((size_t)(b*L_ + l0))*(K_*H_) + k*H_ + h;
    size_t dbase = ((size_t)(b*L_ + l0))*K_ + k;
    int outch = 2*(k*H_ + h) + pi;
    for (int i0 = 0; i0 < CHLEN; i0 += 8) {
        float v[8], d[8];
        #pragma unroll
        for (int j = 0; j < 8; ++j) {
            v[j] = src[base + (size_t)(i0 + j)*(K_*H_)];
            d[j] = pw [dbase + (size_t)(i0 + j)*K_];
        }
        #pragma unroll
        for (int j = 0; j < 8; ++j) {
            acc += v[j]; dacc += d[j];
            float inv = 1.f / fmaxf(dacc, 1e-4f);
            summary[((size_t)(b*L_ + l0 + i0 + j))*NSUM + outch] = acc * inv;
        }
    }
}

// ---------------------------------------------------------------------------
// Fused spectral GEMM + skip-GEMM + gated-SiLU epilogue:
//   spec = summary @ W_sw  (K=1536)  accumulated with
//   skip = x @ W_in[:,780:] (K=768), then
//   y_act[t, k*192+j] = (val) * silu(gate),  val/gate cols = k*384+j / +192.
// A 64-col tile of the 2304 val-columns never crosses a k-group (192 = 3*64),
// so the two B-column ranges are contiguous. Two accumulator sets per thread.
// ---------------------------------------------------------------------------
__global__ __launch_bounds__(256)
void gemm2_fused(const float* __restrict__ summary, const float* __restrict__ Wsw,
                 const float* __restrict__ x, const float* __restrict__ W_in,
                 float* __restrict__ yact)
{
    __shared__ float As[16][68];
    __shared__ float Bsv[16][64];
    __shared__ float Bsg[16][64];
    int tid = threadIdx.x;
    int tx = tid & 15, ty = tid >> 4;
    int m0 = blockIdx.y * 64, n0 = blockIdx.x * 64;
    int kblk = n0 / 192;
    int j0 = n0 % 192;
    int colbase = kblk * 384 + j0;  // val column of this tile's first output col

    float accv[4][4] = {{0.f,0.f,0.f,0.f},{0.f,0.f,0.f,0.f},
                        {0.f,0.f,0.f,0.f},{0.f,0.f,0.f,0.f}};
    float accg[4][4] = {{0.f,0.f,0.f,0.f},{0.f,0.f,0.f,0.f},
                        {0.f,0.f,0.f,0.f},{0.f,0.f,0.f,0.f}};

    int a_m  = tid >> 2;
    int a_k4 = (tid & 3) * 4;
    int b_n  = tid & 63;
    int b_k0 = (tid >> 6) * 4;

    // phase 1 (K=1536, A=summary, B=W_sw) then phase 2 (K=768, A=x, B=W_in+780)
    #pragma unroll 1
    for (int phase = 0; phase < 2; ++phase) {
        const float* Ap  = phase ? x : summary;
        int lda          = phase ? D_ : NSUM;
        int Kd           = phase ? D_ : NSUM;
        const float* Bp  = phase ? (W_in + 780 + colbase) : (Wsw + colbase);
        int ldb          = phase ? 5388 : DST_;
        for (int k0 = 0; k0 < Kd; k0 += 16) {
            float4 av = *reinterpret_cast<const float4*>(
                &Ap[(size_t)(m0 + a_m) * lda + k0 + a_k4]);
            As[a_k4 + 0][a_m] = av.x;
            As[a_k4 + 1][a_m] = av.y;
            As[a_k4 + 2][a_m] = av.z;
            As[a_k4 + 3][a_m] = av.w;
            #pragma unroll
            for (int i = 0; i < 4; ++i) {
                const float* br = &Bp[(size_t)(k0 + b_k0 + i) * ldb + b_n];
                Bsv[b_k0 + i][b_n] = br[0];
                Bsg[b_k0 + i][b_n] = br[192];
            }
            __syncthreads();
            #pragma unroll
            for (int kk = 0; kk < 16; ++kk) {
                float4 a4 = *reinterpret_cast<const float4*>(&As[kk][ty * 4]);
                float4 bv = *reinterpret_cast<const float4*>(&Bsv[kk][tx * 4]);
                float4 bg = *reinterpret_cast<const float4*>(&Bsg[kk][tx * 4]);
                float a[4] = {a4.x, a4.y, a4.z, a4.w};
                #pragma unroll
                for (int i = 0; i < 4; ++i) {
                    accv[i][0] += a[i]*bv.x; accv[i][1] += a[i]*bv.y;
                    accv[i][2] += a[i]*bv.z; accv[i][3] += a[i]*bv.w;
                    accg[i][0] += a[i]*bg.x; accg[i][1] += a[i]*bg.y;
                    accg[i][2] += a[i]*bg.z; accg[i][3] += a[i]*bg.w;
                }
            }
            __syncthreads();
        }
    }

    #pragma unroll
    for (int i = 0; i < 4; ++i) {
        int t = m0 + ty*4 + i;
        float4 v;
        float* vv = &v.x;
        #pragma unroll
        for (int j = 0; j < 4; ++j) {
            float a = accv[i][j];
            float g = accg[i][j];
            vv[j] = a * (g / (1.f + expf(-g)));   // (val) * silu(gate)
        }
        *reinterpret_cast<float4*>(&yact[(size_t)t*NACT + n0 + tx*4]) = v;
    }
}

// ---------------------------------------------------------------------------
extern "C" void kernel_launch(void* const* d_in, const int* in_sizes, int n_in,
                              void* d_out, int out_size, void* d_ws, size_t ws_size,
                              hipStream_t stream)
{
    const float* x         = (const float*)d_in[0];
    const float* W_in      = (const float*)d_in[1];
    const float* conv_w    = (const float*)d_in[2];
    const float* rms_scale = (const float*)d_in[3];
    const float* theta_raw = (const float*)d_in[4];
    const float* dslopes   = (const float*)d_in[5];
    const float* sscale    = (const float*)d_in[6];
    const float* tscale    = (const float*)d_in[7];
    const float* W_sw      = (const float*)d_in[8];
    const float* W_out     = (const float*)d_in[9];
    float* out = (float*)d_out;
    float* ws  = (float*)d_ws;

    // Workspace layout (floats). Total 31,755,264 fl = ~127 MB.
    // yact (18,874,368) aliases zmem+pw+re+part-of-im — all dead by the time
    // gemm2_fused writes it (stream-ordered).
    float* zmem    = ws;                      // NT*780      = 6,389,760
    float* pw      = zmem + (size_t)NT*DMK;   // NT*12       =    98,304
    float* re      = pw   + (size_t)NT*K_;    // NT*768      = 6,291,456
    float* im      = re   + (size_t)NT*K_*H_; // NT*768      = 6,291,456
    float* summary = im   + (size_t)NT*K_*H_; // NT*1536     = 12,582,912
    float* part    = summary + (size_t)NT*NSUM; // 48*16*132 =   101,376
    float* yact    = ws;                      // alias       = 18,874,368

    dim3 blk(256);
    // 1) z_mem = x @ W_in[:, :780]
    gemm_f32<<<dim3(13, 128), blk, 0, stream>>>(x, W_in, zmem,
                                                NT, DMK, D_, D_, 5388, DMK);
    // 2) conv + silu + rmsnorm + phase
    token_kernel<<<dim3(NT), blk, 0, stream>>>(zmem, conv_w, rms_scale, theta_raw,
                                               dslopes, sscale, tscale, pw, re, im);
    // 3) chunked cumsum -> summary
    scan_sums <<<dim3(B_*K_*NCHUNK), dim3(128), 0, stream>>>(pw, re, im, part);
    scan_final<<<dim3(B_*K_*NCHUNK), dim3(128), 0, stream>>>(pw, re, im, part, summary);
    // 4) fused spectral+skip GEMM with gated-SiLU epilogue
    gemm2_fused<<<dim3(NACT/64, 128), blk, 0, stream>>>(summary, W_sw, x, W_in, yact);
    // 5) out = y_act @ W_out
    gemm_f32<<<dim3(12, 128), blk, 0, stream>>>(yact, W_out, out,
                                                NT, D_, NACT, NACT, D_, D_);
}

// Round 3
// 650.164 us; speedup vs baseline: 4.1233x; 4.1233x over previous
//
#include <hip/hip_runtime.h>
#include <hip/hip_bf16.h>

// Problem constants (B,L,D)=(4,2048,768), K=12, M=1, CK=4, H=64
#define B_       4
#define L_       2048
#define D_       768
#define K_       12
#define H_       64
#define CK_      4
#define DIM_MEM_ 768
#define DMK      780        // DIM_MEM + K
#define NT       (B_*L_)    // 8192 tokens
#define NSUM     1536       // 2*K*H  (summary width)
#define NACT     2304       // K*192  (y_act width)
#define NCHUNK   16
#define CHLEN    (L_/NCHUNK)  // 128
#define PSTRIDE  132

typedef __attribute__((ext_vector_type(8))) short          bf16x8;
typedef __attribute__((ext_vector_type(8))) unsigned short u16x8;
typedef __attribute__((ext_vector_type(4))) float          f32x4;

__device__ __forceinline__ ushort f2bf(float v) {
    __hip_bfloat16 h = __float2bfloat16(v);
    return *reinterpret_cast<ushort*>(&h);
}

// ---------------------------------------------------------------------------
// fp32 SIMT GEMM (kept only for gemm1 — error-sensitive exp(score) path).
// ---------------------------------------------------------------------------
__global__ __launch_bounds__(256)
void gemm_f32(const float* __restrict__ A, const float* __restrict__ Bm,
              float* __restrict__ Cm, int M, int N, int Kd,
              int lda, int ldb, int ldc)
{
    __shared__ float As[16][68];
    __shared__ float Bs[16][64];
    int tid = threadIdx.x;
    int tx = tid & 15, ty = tid >> 4;
    int m0 = blockIdx.y * 64, n0 = blockIdx.x * 64;

    float acc[4][4] = {{0.f,0.f,0.f,0.f},{0.f,0.f,0.f,0.f},
                       {0.f,0.f,0.f,0.f},{0.f,0.f,0.f,0.f}};

    int a_m  = tid >> 2;
    int a_k4 = (tid & 3) * 4;
    int b_n  = tid & 63;
    int b_k0 = (tid >> 6) * 4;
    bool nok = (n0 + b_n) < N;

    for (int k0 = 0; k0 < Kd; k0 += 16) {
        float4 av = *reinterpret_cast<const float4*>(
            &A[(size_t)(m0 + a_m) * lda + k0 + a_k4]);
        As[a_k4 + 0][a_m] = av.x;
        As[a_k4 + 1][a_m] = av.y;
        As[a_k4 + 2][a_m] = av.z;
        As[a_k4 + 3][a_m] = av.w;
        #pragma unroll
        for (int i = 0; i < 4; ++i) {
            float v = nok ? Bm[(size_t)(k0 + b_k0 + i) * ldb + n0 + b_n] : 0.f;
            Bs[b_k0 + i][b_n] = v;
        }
        __syncthreads();
        #pragma unroll
        for (int kk = 0; kk < 16; ++kk) {
            float4 a4 = *reinterpret_cast<const float4*>(&As[kk][ty * 4]);
            float4 b4 = *reinterpret_cast<const float4*>(&Bs[kk][tx * 4]);
            acc[0][0] += a4.x*b4.x; acc[0][1] += a4.x*b4.y; acc[0][2] += a4.x*b4.z; acc[0][3] += a4.x*b4.w;
            acc[1][0] += a4.y*b4.x; acc[1][1] += a4.y*b4.y; acc[1][2] += a4.y*b4.z; acc[1][3] += a4.y*b4.w;
            acc[2][0] += a4.z*b4.x; acc[2][1] += a4.z*b4.y; acc[2][2] += a4.z*b4.z; acc[2][3] += a4.z*b4.w;
            acc[3][0] += a4.w*b4.x; acc[3][1] += a4.w*b4.y; acc[3][2] += a4.w*b4.z; acc[3][3] += a4.w*b4.w;
        }
        __syncthreads();
    }
    #pragma unroll
    for (int i = 0; i < 4; ++i)
        #pragma unroll
        for (int j = 0; j < 4; ++j)
            if (n0 + tx*4 + j < N)
                Cm[(size_t)(m0 + ty*4 + i) * ldc + n0 + tx*4 + j] = acc[i][j];
}

// ---------------------------------------------------------------------------
// Weight prep: out[n][k] (bf16, ld=Kd) = W[k][colbase + map(n)], LDS-tiled
// transpose (32x32 tile, +1 pad). map(n) = remap ? (n/192)*384 + n%192 : n.
// ---------------------------------------------------------------------------
__global__ __launch_bounds__(256)
void prep_wt(const float* __restrict__ W, int ldw, int Kd, int colbase, int remap,
             ushort* __restrict__ out)
{
    __shared__ float tile[32][33];
    int n0 = blockIdx.x * 32, k0 = blockIdx.y * 32;
    int tx = threadIdx.x & 31, ty = threadIdx.x >> 5;   // ty 0..7
    int n = n0 + tx;
    int c = colbase + (remap ? (n/192)*384 + (n%192) : n);
    #pragma unroll
    for (int r = 0; r < 4; ++r)
        tile[ty + r*8][tx] = W[(size_t)(k0 + ty + r*8) * ldw + c];
    __syncthreads();
    #pragma unroll
    for (int r = 0; r < 4; ++r)
        out[(size_t)(n0 + ty + r*8) * Kd + k0 + tx] = f2bf(tile[tx][ty + r*8]);
}

__global__ __launch_bounds__(256)
void cast_bf16_vec(const float* __restrict__ in, ushort* __restrict__ out, int n4)
{
    int i = blockIdx.x * blockDim.x + threadIdx.x;
    if (i >= n4) return;
    float4 v = reinterpret_cast<const float4*>(in)[i];
    ushort4 o;
    o.x = f2bf(v.x); o.y = f2bf(v.y); o.z = f2bf(v.z); o.w = f2bf(v.w);
    reinterpret_cast<ushort4*>(out)[i] = o;
}

// ---------------------------------------------------------------------------
// bf16 MFMA GEMM: C[M,N] fp32 = A[M,K] * BT[N,K]^T.
// 128x128 tile, BK=32, 4 waves each 64x64 (4x4 grid of 16x16x32 MFMAs).
// Staging: global_load_dwordx4 -> VGPR -> ds_write_b128 (NO global_load_lds —
// round-2 evidence: g2lds staging diverged on steady-state launches).
// ---------------------------------------------------------------------------
__global__ __launch_bounds__(256)
void gemm_bf16_mfma(const ushort* __restrict__ A, const ushort* __restrict__ BT,
                    float* __restrict__ C, int Kd, int ldc)
{
    __shared__ ushort As[128*32];   // 8 KB
    __shared__ ushort Bs[128*32];   // 8 KB
    int tid = threadIdx.x, lane = tid & 63;
    int lr = lane & 15, quad = lane >> 4;
    int wave = tid >> 6;
    int wr = (wave >> 1) * 64, wc = (wave & 1) * 64;
    int m0 = blockIdx.y * 128, n0 = blockIdx.x * 128;

    f32x4 acc[4][4] = {};

    const ushort* ga0 = A  + (size_t)(m0 + (tid >> 2)) * Kd + (tid & 3) * 8;
    const ushort* ga1 = ga0 + (size_t)64 * Kd;
    const ushort* gb0 = BT + (size_t)(n0 + (tid >> 2)) * Kd + (tid & 3) * 8;
    const ushort* gb1 = gb0 + (size_t)64 * Kd;
    ushort* la0 = As + tid * 8;
    ushort* la1 = la0 + 2048;
    ushort* lb0 = Bs + tid * 8;
    ushort* lb1 = lb0 + 2048;

    for (int k0 = 0; k0 < Kd; k0 += 32) {
        u16x8 va0 = *reinterpret_cast<const u16x8*>(ga0);
        u16x8 va1 = *reinterpret_cast<const u16x8*>(ga1);
        u16x8 vb0 = *reinterpret_cast<const u16x8*>(gb0);
        u16x8 vb1 = *reinterpret_cast<const u16x8*>(gb1);
        ga0 += 32; ga1 += 32; gb0 += 32; gb1 += 32;
        __syncthreads();               // prev iteration's LDS reads complete
        *reinterpret_cast<u16x8*>(la0) = va0;
        *reinterpret_cast<u16x8*>(la1) = va1;
        *reinterpret_cast<u16x8*>(lb0) = vb0;
        *reinterpret_cast<u16x8*>(lb1) = vb1;
        __syncthreads();               // staging visible to all waves
        bf16x8 af[4], bf[4];
        #pragma unroll
        for (int i = 0; i < 4; ++i) {
            af[i] = *reinterpret_cast<const bf16x8*>(As + (wr + i*16 + lr) * 32 + quad * 8);
            bf[i] = *reinterpret_cast<const bf16x8*>(Bs + (wc + i*16 + lr) * 32 + quad * 8);
        }
        #pragma unroll
        for (int i = 0; i < 4; ++i)
            #pragma unroll
            for (int j = 0; j < 4; ++j)
                acc[i][j] = __builtin_amdgcn_mfma_f32_16x16x32_bf16(
                                af[i], bf[j], acc[i][j], 0, 0, 0);
    }

    #pragma unroll
    for (int i = 0; i < 4; ++i)
        #pragma unroll
        for (int j = 0; j < 4; ++j)
            #pragma unroll
            for (int r = 0; r < 4; ++r) {
                int row = m0 + wr + i*16 + quad*4 + r;      // m89-verified C/D map
                int col = n0 + wc + j*16 + lr;
                C[(size_t)row * ldc + col] = acc[i][j][r];
            }
}

// ---------------------------------------------------------------------------
// Fused spectral+skip MFMA GEMM, gated-SiLU epilogue, bf16 output.
// Tile 128(M) x 64(y-cols); two B-tiles (val,gate); two K-phases:
//   phase0: A=summary(K=1536) B=WswT_{v,g};  phase1: A=x(K=768) B=W_inT_{v,g}.
// Register staging (same rationale as gemm_bf16_mfma).
// ---------------------------------------------------------------------------
__global__ __launch_bounds__(256)
void gemm2_mfma(const ushort* __restrict__ Sm, const ushort* __restrict__ Xb,
                const ushort* __restrict__ WsV, const ushort* __restrict__ WsG,
                const ushort* __restrict__ WiV, const ushort* __restrict__ WiG,
                ushort* __restrict__ yact)
{
    __shared__ ushort As[128*32];   // 8 KB
    __shared__ ushort Bv[64*32];    // 4 KB
    __shared__ ushort Bg[64*32];    // 4 KB
    int tid = threadIdx.x, lane = tid & 63;
    int lr = lane & 15, quad = lane >> 4;
    int wave = tid >> 6;
    int wr = (wave >> 1) * 64, wc = (wave & 1) * 32;
    int m0 = blockIdx.y * 128, n0 = blockIdx.x * 64;

    f32x4 av[4][2] = {}, ag[4][2] = {};

    #pragma unroll 1
    for (int phase = 0; phase < 2; ++phase) {
        const ushort* Ap  = phase ? Xb  : Sm;
        const ushort* Bvp = phase ? WiV : WsV;
        const ushort* Bgp = phase ? WiG : WsG;
        int Kd = phase ? 768 : 1536;

        const ushort* ga0 = Ap  + (size_t)(m0 + (tid >> 2)) * Kd + (tid & 3) * 8;
        const ushort* ga1 = ga0 + (size_t)64 * Kd;
        const ushort* gv  = Bvp + (size_t)(n0 + (tid >> 2)) * Kd + (tid & 3) * 8;
        const ushort* gg  = Bgp + (size_t)(n0 + (tid >> 2)) * Kd + (tid & 3) * 8;
        ushort* la0 = As + tid * 8;
        ushort* la1 = la0 + 2048;
        ushort* lv  = Bv + tid * 8;
        ushort* lg  = Bg + tid * 8;

        for (int k0 = 0; k0 < Kd; k0 += 32) {
            u16x8 va0 = *reinterpret_cast<const u16x8*>(ga0);
            u16x8 va1 = *reinterpret_cast<const u16x8*>(ga1);
            u16x8 vv  = *reinterpret_cast<const u16x8*>(gv);
            u16x8 vg  = *reinterpret_cast<const u16x8*>(gg);
            ga0 += 32; ga1 += 32; gv += 32; gg += 32;
            __syncthreads();
            *reinterpret_cast<u16x8*>(la0) = va0;
            *reinterpret_cast<u16x8*>(la1) = va1;
            *reinterpret_cast<u16x8*>(lv)  = vv;
            *reinterpret_cast<u16x8*>(lg)  = vg;
            __syncthreads();
            bf16x8 af[4], bvf[2], bgf[2];
            #pragma unroll
            for (int i = 0; i < 4; ++i)
                af[i] = *reinterpret_cast<const bf16x8*>(As + (wr + i*16 + lr) * 32 + quad * 8);
            #pragma unroll
            for (int j = 0; j < 2; ++j) {
                bvf[j] = *reinterpret_cast<const bf16x8*>(Bv + (wc + j*16 + lr) * 32 + quad * 8);
                bgf[j] = *reinterpret_cast<const bf16x8*>(Bg + (wc + j*16 + lr) * 32 + quad * 8);
            }
            #pragma unroll
            for (int i = 0; i < 4; ++i)
                #pragma unroll
                for (int j = 0; j < 2; ++j) {
                    av[i][j] = __builtin_amdgcn_mfma_f32_16x16x32_bf16(
                                   af[i], bvf[j], av[i][j], 0, 0, 0);
                    ag[i][j] = __builtin_amdgcn_mfma_f32_16x16x32_bf16(
                                   af[i], bgf[j], ag[i][j], 0, 0, 0);
                }
        }
    }

    #pragma unroll
    for (int i = 0; i < 4; ++i)
        #pragma unroll
        for (int j = 0; j < 2; ++j)
            #pragma unroll
            for (int r = 0; r < 4; ++r) {
                int row = m0 + wr + i*16 + quad*4 + r;
                int col = n0 + wc + j*16 + lr;
                float v = av[i][j][r], g = ag[i][j][r];
                float y = v * (g / (1.f + expf(-g)));
                yact[(size_t)row * NACT + col] = f2bf(y);
            }
}

// ---------------------------------------------------------------------------
// Token-local: conv(CK=4)+SiLU+RMSNorm(H)+phase -> pw, re, im
// ---------------------------------------------------------------------------
__global__ __launch_bounds__(256)
void token_kernel(const float* __restrict__ zmem, const float* __restrict__ conv_w,
                  const float* __restrict__ rms_scale, const float* __restrict__ theta_raw,
                  const float* __restrict__ dslopes, const float* __restrict__ sscale,
                  const float* __restrict__ tscale,
                  float* __restrict__ pw, float* __restrict__ re, float* __restrict__ im)
{
    int t = blockIdx.x;
    int b = t >> 11;
    int l = t & (L_ - 1);
    int tid = threadIdx.x;
    int h = tid & 63, kg = tid >> 6;

    __shared__ float s_pw[K_];

    if (tid < K_) {
        float acc = 0.f;
        #pragma unroll
        for (int j = 0; j < CK_; ++j) {
            int ll = l - (CK_ - 1) + j;
            if (ll >= 0)
                acc += zmem[(size_t)(b*L_ + ll)*DMK + DIM_MEM_ + tid]
                     * conv_w[j*DMK + DIM_MEM_ + tid];
        }
        float s  = acc / (1.f + expf(-acc));
        float lp = sscale[tid] * s;
        lp = fminf(10.f, fmaxf(-10.f, lp));
        float slope = log1pf(expf(dslopes[tid]));
        s_pw[tid] = expf(lp - slope * (float)(L_ - 1 - l));
    }

    float kv[3];
    #pragma unroll
    for (int q = 0; q < 3; ++q) {
        int kk = kg + q*4;
        int c = kk*H_ + h;
        float acc = 0.f;
        #pragma unroll
        for (int j = 0; j < CK_; ++j) {
            int ll = l - (CK_ - 1) + j;
            if (ll >= 0)
                acc += zmem[(size_t)(b*L_ + ll)*DMK + c] * conv_w[j*DMK + c];
        }
        kv[q] = acc / (1.f + expf(-acc));
    }
    __syncthreads();

    #pragma unroll
    for (int q = 0; q < 3; ++q) {
        int kk = kg + q*4;
        float v = kv[q];
        float ss = v * v;
        #pragma unroll
        for (int off = 32; off > 0; off >>= 1)
            ss += __shfl_xor(ss, off, 64);
        float kn = v * rsqrtf(ss * (1.f/64.f) + 1e-6f) * rms_scale[h];
        float th = 0.001f + 2.999f * (1.f / (1.f + expf(-theta_raw[kk*H_ + h])));
        float phi = tanhf(kn * tscale[kk]) * th;
        float kvw = kn * s_pw[kk];
        re[(size_t)t*(K_*H_) + kk*H_ + h] = kvw * cosf(phi);
        im[(size_t)t*(K_*H_) + kk*H_ + h] = kvw * sinf(phi);
    }
    if (tid < K_) pw[(size_t)t*K_ + tid] = s_pw[tid];
}

// ---------------------------------------------------------------------------
// Chunked scan pass 1
// ---------------------------------------------------------------------------
__global__ __launch_bounds__(128)
void scan_sums(const float* __restrict__ pw, const float* __restrict__ re,
               const float* __restrict__ im, float* __restrict__ part)
{
    int blk = blockIdx.x;
    int chunk = blk & (NCHUNK - 1);
    int bk = blk >> 4;
    int k = bk % K_;
    int b = bk / K_;
    int tid = threadIdx.x;
    int h = tid & 63;
    const float* __restrict__ src = (tid >> 6) ? im : re;
    int l0 = chunk * CHLEN;

    size_t base  = ((size_t)(b*L_ + l0))*(K_*H_) + k*H_ + h;
    size_t dbase = ((size_t)(b*L_ + l0))*K_ + k;
    float s = 0.f, ds = 0.f;
    for (int i0 = 0; i0 < CHLEN; i0 += 8) {
        float v[8], d[8];
        #pragma unroll
        for (int j = 0; j < 8; ++j) {
            v[j] = src[base + (size_t)(i0 + j)*(K_*H_)];
            d[j] = pw [dbase + (size_t)(i0 + j)*K_];
        }
        #pragma unroll
        for (int j = 0; j < 8; ++j) { s += v[j]; ds += d[j]; }
    }
    size_t pb = ((size_t)bk * NCHUNK + chunk) * PSTRIDE;
    part[pb + tid] = s;
    if (tid == 0) part[pb + 128] = ds;
}

// ---------------------------------------------------------------------------
// Chunked scan pass 2: emit summary directly as bf16.
// ---------------------------------------------------------------------------
__global__ __launch_bounds__(128)
void scan_final(const float* __restrict__ pw, const float* __restrict__ re,
                const float* __restrict__ im, const float* __restrict__ part,
                ushort* __restrict__ summary)
{
    int blk = blockIdx.x;
    int chunk = blk & (NCHUNK - 1);
    int bk = blk >> 4;
    int k = bk % K_;
    int b = bk / K_;
    int tid = threadIdx.x;
    int h = tid & 63;
    int pi = tid >> 6;
    const float* __restrict__ src = pi ? im : re;
    int l0 = chunk * CHLEN;

    float acc = 0.f, dacc = 0.f;
    size_t pb0 = (size_t)bk * NCHUNK * PSTRIDE;
    for (int cn = 0; cn < chunk; ++cn) {
        acc  += part[pb0 + (size_t)cn*PSTRIDE + tid];
        dacc += part[pb0 + (size_t)cn*PSTRIDE + 128];
    }

    size_t base  = ((size_t)(b*L_ + l0))*(K_*H_) + k*H_ + h;
    size_t dbase = ((size_t)(b*L_ + l0))*K_ + k;
    int outch = 2*(k*H_ + h) + pi;
    for (int i0 = 0; i0 < CHLEN; i0 += 8) {
        float v[8], d[8];
        #pragma unroll
        for (int j = 0; j < 8; ++j) {
            v[j] = src[base + (size_t)(i0 + j)*(K_*H_)];
            d[j] = pw [dbase + (size_t)(i0 + j)*K_];
        }
        #pragma unroll
        for (int j = 0; j < 8; ++j) {
            acc += v[j]; dacc += d[j];
            float inv = 1.f / fmaxf(dacc, 1e-4f);
            summary[((size_t)(b*L_ + l0 + i0 + j))*NSUM + outch] = f2bf(acc * inv);
        }
    }
}

// ---------------------------------------------------------------------------
extern "C" void kernel_launch(void* const* d_in, const int* in_sizes, int n_in,
                              void* d_out, int out_size, void* d_ws, size_t ws_size,
                              hipStream_t stream)
{
    const float* x         = (const float*)d_in[0];
    const float* W_in      = (const float*)d_in[1];
    const float* conv_w    = (const float*)d_in[2];
    const float* rms_scale = (const float*)d_in[3];
    const float* theta_raw = (const float*)d_in[4];
    const float* dslopes   = (const float*)d_in[5];
    const float* sscale    = (const float*)d_in[6];
    const float* tscale    = (const float*)d_in[7];
    const float* W_sw      = (const float*)d_in[8];
    const float* W_out     = (const float*)d_in[9];
    float* out = (float*)d_out;
    char* ws   = (char*)d_ws;

    // Workspace (byte offsets, all 256-aligned). Peak ~114 MB (< proven 127 MB).
    float*  zmem    = (float*) (ws + 0);           // NT*780 f32   = 25,559,040 B
    ushort* summary = (ushort*)(ws + 0);           // alias (zmem dead): 25,165,824 B
    float*  pw      = (float*) (ws + 25559040);    //   393,216 B
    float*  re      = (float*) (ws + 25952256);    // 25,165,824 B
    float*  im      = (float*) (ws + 51118080);    // 25,165,824 B
    ushort* yact    = (ushort*)(ws + 25952256);    // alias re+im (dead): 37,748,736 B
    float*  part    = (float*) (ws + 76283904);    //   405,504 B
    ushort* xb      = (ushort*)(ws + 76689408);    // 12,582,912 B
    ushort* WiV     = (ushort*)(ws + 89272320);    //  3,538,944 B  [2304][768]
    ushort* WiG     = (ushort*)(ws + 92811264);    //  3,538,944 B
    ushort* WsV     = (ushort*)(ws + 96350208);    //  7,077,888 B  [2304][1536]
    ushort* WsG     = (ushort*)(ws + 103428096);   //  7,077,888 B
    ushort* WoT     = (ushort*)(ws + 110505984);   //  3,538,944 B  [768][2304]

    dim3 blk(256);
    // 0) preps: x->bf16; transposed/remapped bf16 weights
    cast_bf16_vec<<<dim3((NT*D_/4 + 255)/256), blk, 0, stream>>>(x, xb, NT*D_/4);
    prep_wt<<<dim3(NACT/32, D_/32),    blk, 0, stream>>>(W_in, 5388, D_,   780, 1, WiV);
    prep_wt<<<dim3(NACT/32, D_/32),    blk, 0, stream>>>(W_in, 5388, D_,   972, 1, WiG);
    prep_wt<<<dim3(NACT/32, NSUM/32),  blk, 0, stream>>>(W_sw, 4608, NSUM,   0, 1, WsV);
    prep_wt<<<dim3(NACT/32, NSUM/32),  blk, 0, stream>>>(W_sw, 4608, NSUM, 192, 1, WsG);
    prep_wt<<<dim3(D_/32,   NACT/32),  blk, 0, stream>>>(W_out, 768, NACT,   0, 0, WoT);
    // 1) z_mem = x @ W_in[:, :780]  (fp32 — exp-sensitive path)
    gemm_f32<<<dim3(13, 128), blk, 0, stream>>>(x, W_in, zmem,
                                                NT, DMK, D_, D_, 5388, DMK);
    // 2) conv + silu + rmsnorm + phase
    token_kernel<<<dim3(NT), blk, 0, stream>>>(zmem, conv_w, rms_scale, theta_raw,
                                               dslopes, sscale, tscale, pw, re, im);
    // 3) chunked cumsum -> summary (bf16)
    scan_sums <<<dim3(B_*K_*NCHUNK), dim3(128), 0, stream>>>(pw, re, im, part);
    scan_final<<<dim3(B_*K_*NCHUNK), dim3(128), 0, stream>>>(pw, re, im, part, summary);
    // 4) fused spectral+skip MFMA GEMM with gated-SiLU epilogue -> yact (bf16)
    gemm2_mfma<<<dim3(NACT/64, NT/128), blk, 0, stream>>>(summary, xb,
                                                          WsV, WsG, WiV, WiG, yact);
    // 5) out = yact @ W_out  (MFMA)
    gemm_bf16_mfma<<<dim3(D_/128, NT/128), blk, 0, stream>>>(yact, WoT, out, NACT, D_);
}

// Round 4
// 505.605 us; speedup vs baseline: 5.3022x; 1.2859x over previous
//
#include <hip/hip_runtime.h>
#include <hip/hip_bf16.h>

// Problem constants (B,L,D)=(4,2048,768), K=12, M=1, CK=4, H=64
#define B_       4
#define L_       2048
#define D_       768
#define K_       12
#define H_       64
#define CK_      4
#define DIM_MEM_ 768
#define DMK      780        // DIM_MEM + K
#define NT       (B_*L_)    // 8192 tokens
#define NSUM     1536       // 2*K*H  (summary width)
#define NACT     2304       // K*192  (y_act width)
#define NCHUNK   16
#define CHLEN    (L_/NCHUNK)  // 128
#define PSTRIDE  132

typedef __attribute__((ext_vector_type(8))) short          bf16x8;
typedef __attribute__((ext_vector_type(8))) unsigned short u16x8;
typedef __attribute__((ext_vector_type(4))) float          f32x4;

__device__ __forceinline__ ushort f2bf(float v) {
    __hip_bfloat16 h = __float2bfloat16(v);
    return *reinterpret_cast<ushort*>(&h);
}

// ---------------------------------------------------------------------------
// Merged prep: 6 transpose-cast jobs (32x32 LDS tiles) + x->bf16 cast, one
// launch. Each block resolves its job from the cumulative-start table.
// out[n][k] (bf16, ld=Kd) = W[k][colbase + map(n)];
// map(n) = remap ? (n/192)*384 + n%192 : n.
// ---------------------------------------------------------------------------
struct PrepJobs {
    const float* W[6];
    ushort*      out[6];
    int ldw[6], Kd[6], colbase[6], remap[6], ntx[6];
    int start[7];                 // start[6] = begin of cast blocks
    const float* cast_in;
    ushort*      cast_out;
    int n4;
};

__global__ __launch_bounds__(256)
void prep_all(PrepJobs J)
{
    int blk = blockIdx.x;
    if (blk >= J.start[6]) {                       // cast job
        int i = (blk - J.start[6]) * 256 + threadIdx.x;
        if (i < J.n4) {
            float4 v = reinterpret_cast<const float4*>(J.cast_in)[i];
            ushort4 o;
            o.x = f2bf(v.x); o.y = f2bf(v.y); o.z = f2bf(v.z); o.w = f2bf(v.w);
            reinterpret_cast<ushort4*>(J.cast_out)[i] = o;
        }
        return;
    }
    int j = 0;
    while (blk >= J.start[j + 1]) ++j;
    int rel = blk - J.start[j];
    int ntx = J.ntx[j];
    int n0 = (rel % ntx) * 32, k0 = (rel / ntx) * 32;
    const float* W = J.W[j];
    int ldw = J.ldw[j], Kd = J.Kd[j], colbase = J.colbase[j], remap = J.remap[j];
    ushort* out = J.out[j];

    __shared__ float tile[32][33];
    int tx = threadIdx.x & 31, ty = threadIdx.x >> 5;   // ty 0..7
    int n = n0 + tx;
    int c = colbase + (remap ? (n/192)*384 + (n%192) : n);
    #pragma unroll
    for (int r = 0; r < 4; ++r)
        tile[ty + r*8][tx] = W[(size_t)(k0 + ty + r*8) * ldw + c];
    __syncthreads();
    #pragma unroll
    for (int r = 0; r < 4; ++r)
        out[(size_t)(n0 + ty + r*8) * Kd + k0 + tx] = f2bf(tile[tx][ty + r*8]);
}

// ---------------------------------------------------------------------------
// bf16 MFMA GEMM: C[M,N] fp32 = A[M,K] * BT[Nr,K]^T, write guard col<N
// (BT may have padded rows beyond N). 128x128 tile, BK=32, 4 waves each
// 64x64 (4x4 grid of 16x16x32 MFMAs). Register staging (NO global_load_lds —
// round-2 evidence: g2lds staging diverged on steady-state launches).
// ---------------------------------------------------------------------------
__global__ __launch_bounds__(256)
void gemm_bf16_mfma(const ushort* __restrict__ A, const ushort* __restrict__ BT,
                    float* __restrict__ C, int Kd, int N, int ldc)
{
    __shared__ ushort As[128*32];   // 8 KB
    __shared__ ushort Bs[128*32];   // 8 KB
    int tid = threadIdx.x, lane = tid & 63;
    int lr = lane & 15, quad = lane >> 4;
    int wave = tid >> 6;
    int wr = (wave >> 1) * 64, wc = (wave & 1) * 64;
    int m0 = blockIdx.y * 128, n0 = blockIdx.x * 128;

    f32x4 acc[4][4] = {};

    const ushort* ga0 = A  + (size_t)(m0 + (tid >> 2)) * Kd + (tid & 3) * 8;
    const ushort* ga1 = ga0 + (size_t)64 * Kd;
    const ushort* gb0 = BT + (size_t)(n0 + (tid >> 2)) * Kd + (tid & 3) * 8;
    const ushort* gb1 = gb0 + (size_t)64 * Kd;
    ushort* la0 = As + tid * 8;
    ushort* la1 = la0 + 2048;
    ushort* lb0 = Bs + tid * 8;
    ushort* lb1 = lb0 + 2048;

    for (int k0 = 0; k0 < Kd; k0 += 32) {
        u16x8 va0 = *reinterpret_cast<const u16x8*>(ga0);
        u16x8 va1 = *reinterpret_cast<const u16x8*>(ga1);
        u16x8 vb0 = *reinterpret_cast<const u16x8*>(gb0);
        u16x8 vb1 = *reinterpret_cast<const u16x8*>(gb1);
        ga0 += 32; ga1 += 32; gb0 += 32; gb1 += 32;
        __syncthreads();               // prev iteration's LDS reads complete
        *reinterpret_cast<u16x8*>(la0) = va0;
        *reinterpret_cast<u16x8*>(la1) = va1;
        *reinterpret_cast<u16x8*>(lb0) = vb0;
        *reinterpret_cast<u16x8*>(lb1) = vb1;
        __syncthreads();               // staging visible to all waves
        bf16x8 af[4], bf[4];
        #pragma unroll
        for (int i = 0; i < 4; ++i) {
            af[i] = *reinterpret_cast<const bf16x8*>(As + (wr + i*16 + lr) * 32 + quad * 8);
            bf[i] = *reinterpret_cast<const bf16x8*>(Bs + (wc + i*16 + lr) * 32 + quad * 8);
        }
        #pragma unroll
        for (int i = 0; i < 4; ++i)
            #pragma unroll
            for (int j = 0; j < 4; ++j)
                acc[i][j] = __builtin_amdgcn_mfma_f32_16x16x32_bf16(
                                af[i], bf[j], acc[i][j], 0, 0, 0);
    }

    #pragma unroll
    for (int i = 0; i < 4; ++i)
        #pragma unroll
        for (int j = 0; j < 4; ++j)
            #pragma unroll
            for (int r = 0; r < 4; ++r) {
                int row = m0 + wr + i*16 + quad*4 + r;      // m89-verified C/D map
                int col = n0 + wc + j*16 + lr;
                if (col < N)
                    C[(size_t)row * ldc + col] = acc[i][j][r];
            }
}

// ---------------------------------------------------------------------------
// Fused spectral+skip MFMA GEMM, gated-SiLU epilogue, bf16 output.
// Tile 128(M) x 64(y-cols); two B-tiles (val,gate); two K-phases:
//   phase0: A=summary(K=1536) B=WswT_{v,g};  phase1: A=x(K=768) B=W_inT_{v,g}.
// Register staging (same rationale as gemm_bf16_mfma).
// ---------------------------------------------------------------------------
__global__ __launch_bounds__(256)
void gemm2_mfma(const ushort* __restrict__ Sm, const ushort* __restrict__ Xb,
                const ushort* __restrict__ WsV, const ushort* __restrict__ WsG,
                const ushort* __restrict__ WiV, const ushort* __restrict__ WiG,
                ushort* __restrict__ yact)
{
    __shared__ ushort As[128*32];   // 8 KB
    __shared__ ushort Bv[64*32];    // 4 KB
    __shared__ ushort Bg[64*32];    // 4 KB
    int tid = threadIdx.x, lane = tid & 63;
    int lr = lane & 15, quad = lane >> 4;
    int wave = tid >> 6;
    int wr = (wave >> 1) * 64, wc = (wave & 1) * 32;
    int m0 = blockIdx.y * 128, n0 = blockIdx.x * 64;

    f32x4 av[4][2] = {}, ag[4][2] = {};

    #pragma unroll 1
    for (int phase = 0; phase < 2; ++phase) {
        const ushort* Ap  = phase ? Xb  : Sm;
        const ushort* Bvp = phase ? WiV : WsV;
        const ushort* Bgp = phase ? WiG : WsG;
        int Kd = phase ? 768 : 1536;

        const ushort* ga0 = Ap  + (size_t)(m0 + (tid >> 2)) * Kd + (tid & 3) * 8;
        const ushort* ga1 = ga0 + (size_t)64 * Kd;
        const ushort* gv  = Bvp + (size_t)(n0 + (tid >> 2)) * Kd + (tid & 3) * 8;
        const ushort* gg  = Bgp + (size_t)(n0 + (tid >> 2)) * Kd + (tid & 3) * 8;
        ushort* la0 = As + tid * 8;
        ushort* la1 = la0 + 2048;
        ushort* lv  = Bv + tid * 8;
        ushort* lg  = Bg + tid * 8;

        for (int k0 = 0; k0 < Kd; k0 += 32) {
            u16x8 va0 = *reinterpret_cast<const u16x8*>(ga0);
            u16x8 va1 = *reinterpret_cast<const u16x8*>(ga1);
            u16x8 vv  = *reinterpret_cast<const u16x8*>(gv);
            u16x8 vg  = *reinterpret_cast<const u16x8*>(gg);
            ga0 += 32; ga1 += 32; gv += 32; gg += 32;
            __syncthreads();
            *reinterpret_cast<u16x8*>(la0) = va0;
            *reinterpret_cast<u16x8*>(la1) = va1;
            *reinterpret_cast<u16x8*>(lv)  = vv;
            *reinterpret_cast<u16x8*>(lg)  = vg;
            __syncthreads();
            bf16x8 af[4], bvf[2], bgf[2];
            #pragma unroll
            for (int i = 0; i < 4; ++i)
                af[i] = *reinterpret_cast<const bf16x8*>(As + (wr + i*16 + lr) * 32 + quad * 8);
            #pragma unroll
            for (int j = 0; j < 2; ++j) {
                bvf[j] = *reinterpret_cast<const bf16x8*>(Bv + (wc + j*16 + lr) * 32 + quad * 8);
                bgf[j] = *reinterpret_cast<const bf16x8*>(Bg + (wc + j*16 + lr) * 32 + quad * 8);
            }
            #pragma unroll
            for (int i = 0; i < 4; ++i)
                #pragma unroll
                for (int j = 0; j < 2; ++j) {
                    av[i][j] = __builtin_amdgcn_mfma_f32_16x16x32_bf16(
                                   af[i], bvf[j], av[i][j], 0, 0, 0);
                    ag[i][j] = __builtin_amdgcn_mfma_f32_16x16x32_bf16(
                                   af[i], bgf[j], ag[i][j], 0, 0, 0);
                }
        }
    }

    #pragma unroll
    for (int i = 0; i < 4; ++i)
        #pragma unroll
        for (int j = 0; j < 2; ++j)
            #pragma unroll
            for (int r = 0; r < 4; ++r) {
                int row = m0 + wr + i*16 + quad*4 + r;
                int col = n0 + wc + j*16 + lr;
                float v = av[i][j][r], g = ag[i][j][r];
                float y = v * (g / (1.f + expf(-g)));
                yact[(size_t)row * NACT + col] = f2bf(y);
            }
}

// ---------------------------------------------------------------------------
// Token-local: conv(CK=4)+SiLU+RMSNorm(H)+phase -> pw, re, im
// ---------------------------------------------------------------------------
__global__ __launch_bounds__(256)
void token_kernel(const float* __restrict__ zmem, const float* __restrict__ conv_w,
                  const float* __restrict__ rms_scale, const float* __restrict__ theta_raw,
                  const float* __restrict__ dslopes, const float* __restrict__ sscale,
                  const float* __restrict__ tscale,
                  float* __restrict__ pw, float* __restrict__ re, float* __restrict__ im)
{
    int t = blockIdx.x;
    int b = t >> 11;
    int l = t & (L_ - 1);
    int tid = threadIdx.x;
    int h = tid & 63, kg = tid >> 6;

    __shared__ float s_pw[K_];

    if (tid < K_) {
        float acc = 0.f;
        #pragma unroll
        for (int j = 0; j < CK_; ++j) {
            int ll = l - (CK_ - 1) + j;
            if (ll >= 0)
                acc += zmem[(size_t)(b*L_ + ll)*DMK + DIM_MEM_ + tid]
                     * conv_w[j*DMK + DIM_MEM_ + tid];
        }
        float s  = acc / (1.f + expf(-acc));
        float lp = sscale[tid] * s;
        lp = fminf(10.f, fmaxf(-10.f, lp));
        float slope = log1pf(expf(dslopes[tid]));
        s_pw[tid] = expf(lp - slope * (float)(L_ - 1 - l));
    }

    float kv[3];
    #pragma unroll
    for (int q = 0; q < 3; ++q) {
        int kk = kg + q*4;
        int c = kk*H_ + h;
        float acc = 0.f;
        #pragma unroll
        for (int j = 0; j < CK_; ++j) {
            int ll = l - (CK_ - 1) + j;
            if (ll >= 0)
                acc += zmem[(size_t)(b*L_ + ll)*DMK + c] * conv_w[j*DMK + c];
        }
        kv[q] = acc / (1.f + expf(-acc));
    }
    __syncthreads();

    #pragma unroll
    for (int q = 0; q < 3; ++q) {
        int kk = kg + q*4;
        float v = kv[q];
        float ss = v * v;
        #pragma unroll
        for (int off = 32; off > 0; off >>= 1)
            ss += __shfl_xor(ss, off, 64);
        float kn = v * rsqrtf(ss * (1.f/64.f) + 1e-6f) * rms_scale[h];
        float th = 0.001f + 2.999f * (1.f / (1.f + expf(-theta_raw[kk*H_ + h])));
        float phi = tanhf(kn * tscale[kk]) * th;
        float kvw = kn * s_pw[kk];
        re[(size_t)t*(K_*H_) + kk*H_ + h] = kvw * cosf(phi);
        im[(size_t)t*(K_*H_) + kk*H_ + h] = kvw * sinf(phi);
    }
    if (tid < K_) pw[(size_t)t*K_ + tid] = s_pw[tid];
}

// ---------------------------------------------------------------------------
// Chunked scan pass 1
// ---------------------------------------------------------------------------
__global__ __launch_bounds__(128)
void scan_sums(const float* __restrict__ pw, const float* __restrict__ re,
               const float* __restrict__ im, float* __restrict__ part)
{
    int blk = blockIdx.x;
    int chunk = blk & (NCHUNK - 1);
    int bk = blk >> 4;
    int k = bk % K_;
    int b = bk / K_;
    int tid = threadIdx.x;
    int h = tid & 63;
    const float* __restrict__ src = (tid >> 6) ? im : re;
    int l0 = chunk * CHLEN;

    size_t base  = ((size_t)(b*L_ + l0))*(K_*H_) + k*H_ + h;
    size_t dbase = ((size_t)(b*L_ + l0))*K_ + k;
    float s = 0.f, ds = 0.f;
    for (int i0 = 0; i0 < CHLEN; i0 += 8) {
        float v[8], d[8];
        #pragma unroll
        for (int j = 0; j < 8; ++j) {
            v[j] = src[base + (size_t)(i0 + j)*(K_*H_)];
            d[j] = pw [dbase + (size_t)(i0 + j)*K_];
        }
        #pragma unroll
        for (int j = 0; j < 8; ++j) { s += v[j]; ds += d[j]; }
    }
    size_t pb = ((size_t)bk * NCHUNK + chunk) * PSTRIDE;
    part[pb + tid] = s;
    if (tid == 0) part[pb + 128] = ds;
}

// ---------------------------------------------------------------------------
// Chunked scan pass 2: emit summary directly as bf16.
// ---------------------------------------------------------------------------
__global__ __launch_bounds__(128)
void scan_final(const float* __restrict__ pw, const float* __restrict__ re,
                const float* __restrict__ im, const float* __restrict__ part,
                ushort* __restrict__ summary)
{
    int blk = blockIdx.x;
    int chunk = blk & (NCHUNK - 1);
    int bk = blk >> 4;
    int k = bk % K_;
    int b = bk / K_;
    int tid = threadIdx.x;
    int h = tid & 63;
    int pi = tid >> 6;
    const float* __restrict__ src = pi ? im : re;
    int l0 = chunk * CHLEN;

    float acc = 0.f, dacc = 0.f;
    size_t pb0 = (size_t)bk * NCHUNK * PSTRIDE;
    for (int cn = 0; cn < chunk; ++cn) {
        acc  += part[pb0 + (size_t)cn*PSTRIDE + tid];
        dacc += part[pb0 + (size_t)cn*PSTRIDE + 128];
    }

    size_t base  = ((size_t)(b*L_ + l0))*(K_*H_) + k*H_ + h;
    size_t dbase = ((size_t)(b*L_ + l0))*K_ + k;
    int outch = 2*(k*H_ + h) + pi;
    for (int i0 = 0; i0 < CHLEN; i0 += 8) {
        float v[8], d[8];
        #pragma unroll
        for (int j = 0; j < 8; ++j) {
            v[j] = src[base + (size_t)(i0 + j)*(K_*H_)];
            d[j] = pw [dbase + (size_t)(i0 + j)*K_];
        }
        #pragma unroll
        for (int j = 0; j < 8; ++j) {
            acc += v[j]; dacc += d[j];
            float inv = 1.f / fmaxf(dacc, 1e-4f);
            summary[((size_t)(b*L_ + l0 + i0 + j))*NSUM + outch] = f2bf(acc * inv);
        }
    }
}

// ---------------------------------------------------------------------------
extern "C" void kernel_launch(void* const* d_in, const int* in_sizes, int n_in,
                              void* d_out, int out_size, void* d_ws, size_t ws_size,
                              hipStream_t stream)
{
    const float* x         = (const float*)d_in[0];
    const float* W_in      = (const float*)d_in[1];
    const float* conv_w    = (const float*)d_in[2];
    const float* rms_scale = (const float*)d_in[3];
    const float* theta_raw = (const float*)d_in[4];
    const float* dslopes   = (const float*)d_in[5];
    const float* sscale    = (const float*)d_in[6];
    const float* tscale    = (const float*)d_in[7];
    const float* W_sw      = (const float*)d_in[8];
    const float* W_out     = (const float*)d_in[9];
    float* out = (float*)d_out;
    char* ws   = (char*)d_ws;

    // Workspace (byte offsets, all 256-aligned). Peak ~115.4 MB (< proven 127).
    float*  zmem    = (float*) (ws + 0);           // NT*780 f32   = 25,559,040 B
    ushort* summary = (ushort*)(ws + 0);           // alias (zmem dead): 25,165,824 B
    float*  pw      = (float*) (ws + 25559040);    //   393,216 B
    float*  re      = (float*) (ws + 25952256);    // 25,165,824 B
    float*  im      = (float*) (ws + 51118080);    // 25,165,824 B
    ushort* yact    = (ushort*)(ws + 25952256);    // alias re+im (dead): 37,748,736 B
    float*  part    = (float*) (ws + 76283904);    //   405,504 B
    ushort* xb      = (ushort*)(ws + 76689408);    // 12,582,912 B
    ushort* WiV     = (ushort*)(ws + 89272320);    //  3,538,944 B  [2304][768]
    ushort* WiG     = (ushort*)(ws + 92811264);    //  3,538,944 B
    ushort* WsV     = (ushort*)(ws + 96350208);    //  7,077,888 B  [2304][1536]
    ushort* WsG     = (ushort*)(ws + 103428096);   //  7,077,888 B
    ushort* WoT     = (ushort*)(ws + 110505984);   //  3,538,944 B  [768][2304]
    ushort* WimT    = (ushort*)(ws + 114044928);   //  1,376,256 B  [896][768] (pad)

    // ---- merged prep job table ----
    PrepJobs J;
    // job 0: WiV  (W_in cols 780.. remapped)  72 x 24 tiles
    J.W[0]=W_in;  J.out[0]=WiV;  J.ldw[0]=5388; J.Kd[0]=768;  J.colbase[0]=780; J.remap[0]=1; J.ntx[0]=72;
    // job 1: WiG
    J.W[1]=W_in;  J.out[1]=WiG;  J.ldw[1]=5388; J.Kd[1]=768;  J.colbase[1]=972; J.remap[1]=1; J.ntx[1]=72;
    // job 2: WsV  72 x 48
    J.W[2]=W_sw;  J.out[2]=WsV;  J.ldw[2]=4608; J.Kd[2]=1536; J.colbase[2]=0;   J.remap[2]=1; J.ntx[2]=72;
    // job 3: WsG
    J.W[3]=W_sw;  J.out[3]=WsG;  J.ldw[3]=4608; J.Kd[3]=1536; J.colbase[3]=192; J.remap[3]=1; J.ntx[3]=72;
    // job 4: WoT  24 x 72
    J.W[4]=W_out; J.out[4]=WoT;  J.ldw[4]=768;  J.Kd[4]=2304; J.colbase[4]=0;   J.remap[4]=0; J.ntx[4]=24;
    // job 5: WimT 28 x 24 (rows 780..895 hold unused-but-in-bounds data)
    J.W[5]=W_in;  J.out[5]=WimT; J.ldw[5]=5388; J.Kd[5]=768;  J.colbase[5]=0;   J.remap[5]=0; J.ntx[5]=28;
    int tiles[6] = {72*24, 72*24, 72*48, 72*48, 24*72, 28*24};
    J.start[0] = 0;
    for (int j = 0; j < 6; ++j) J.start[j+1] = J.start[j] + tiles[j];
    J.cast_in = x; J.cast_out = xb; J.n4 = NT*D_/4;          // 393,216 float4s
    int nblk = J.start[6] + (J.n4 + 255)/256;                 // 12768 + 1536

    dim3 blk(256);
    // 0) all preps in one launch
    prep_all<<<dim3(nblk), blk, 0, stream>>>(J);
    // 1) z_mem = x @ W_in[:, :780]  (bf16 MFMA, col-guarded at 780)
    gemm_bf16_mfma<<<dim3(7, 64), blk, 0, stream>>>(xb, WimT, zmem, 768, 780, 780);
    // 2) conv + silu + rmsnorm + phase
    token_kernel<<<dim3(NT), blk, 0, stream>>>(zmem, conv_w, rms_scale, theta_raw,
                                               dslopes, sscale, tscale, pw, re, im);
    // 3) chunked cumsum -> summary (bf16)
    scan_sums <<<dim3(B_*K_*NCHUNK), dim3(128), 0, stream>>>(pw, re, im, part);
    scan_final<<<dim3(B_*K_*NCHUNK), dim3(128), 0, stream>>>(pw, re, im, part, summary);
    // 4) fused spectral+skip MFMA GEMM with gated-SiLU epilogue -> yact (bf16)
    gemm2_mfma<<<dim3(NACT/64, NT/128), blk, 0, stream>>>(summary, xb,
                                                          WsV, WsG, WiV, WiG, yact);
    // 5) out = yact @ W_out  (MFMA)
    gemm_bf16_mfma<<<dim3(6, 64), blk, 0, stream>>>(yact, WoT, out, 2304, 768, 768);
}

// Round 5
// 499.218 us; speedup vs baseline: 5.3700x; 1.0128x over previous
//
#include <hip/hip_runtime.h>
#include <hip/hip_bf16.h>

// Problem constants (B,L,D)=(4,2048,768), K=12, M=1, CK=4, H=64
#define B_       4
#define L_       2048
#define D_       768
#define K_       12
#define H_       64
#define CK_      4
#define DIM_MEM_ 768
#define DMK      780        // DIM_MEM + K
#define NT       (B_*L_)    // 8192 tokens
#define NSUM     1536       // 2*K*H  (summary width)
#define NACT     2304       // K*192  (y_act width)
#define NCHUNK   16
#define CHLEN    (L_/NCHUNK)  // 128
#define PSTRIDE  132

typedef __attribute__((ext_vector_type(8))) short          bf16x8;
typedef __attribute__((ext_vector_type(8))) unsigned short u16x8;
typedef __attribute__((ext_vector_type(4))) float          f32x4;

__device__ __forceinline__ ushort f2bf(float v) {
    __hip_bfloat16 h = __float2bfloat16(v);
    return *reinterpret_cast<ushort*>(&h);
}
// fast tanh via hw exp; safe for any x (t->0 as |x|->inf)
__device__ __forceinline__ float tanh_fast(float x) {
    float t = __expf(-2.f * fabsf(x));
    float r = (1.f - t) / (1.f + t);
    return copysignf(r, x);
}

// ---------------------------------------------------------------------------
// Merged prep: 6 transpose-cast jobs (32x32 LDS tiles) + x->bf16 cast, one
// launch. out[n][k] (bf16, ld=Kd) = W[k][colbase + map(n)];
// map(n) = remap ? (n/192)*384 + n%192 : n.
// ---------------------------------------------------------------------------
struct PrepJobs {
    const float* W[6];
    ushort*      out[6];
    int ldw[6], Kd[6], colbase[6], remap[6], ntx[6];
    int start[7];                 // start[6] = begin of cast blocks
    const float* cast_in;
    ushort*      cast_out;
    int n4;
};

__global__ __launch_bounds__(256)
void prep_all(PrepJobs J)
{
    int blk = blockIdx.x;
    if (blk >= J.start[6]) {                       // cast job
        int i = (blk - J.start[6]) * 256 + threadIdx.x;
        if (i < J.n4) {
            float4 v = reinterpret_cast<const float4*>(J.cast_in)[i];
            ushort4 o;
            o.x = f2bf(v.x); o.y = f2bf(v.y); o.z = f2bf(v.z); o.w = f2bf(v.w);
            reinterpret_cast<ushort4*>(J.cast_out)[i] = o;
        }
        return;
    }
    int j = 0;
    while (blk >= J.start[j + 1]) ++j;
    int rel = blk - J.start[j];
    int ntx = J.ntx[j];
    int n0 = (rel % ntx) * 32, k0 = (rel / ntx) * 32;
    const float* W = J.W[j];
    int ldw = J.ldw[j], Kd = J.Kd[j], colbase = J.colbase[j], remap = J.remap[j];
    ushort* out = J.out[j];

    __shared__ float tile[32][33];
    int tx = threadIdx.x & 31, ty = threadIdx.x >> 5;   // ty 0..7
    int n = n0 + tx;
    int c = colbase + (remap ? (n/192)*384 + (n%192) : n);
    #pragma unroll
    for (int r = 0; r < 4; ++r)
        tile[ty + r*8][tx] = W[(size_t)(k0 + ty + r*8) * ldw + c];
    __syncthreads();
    #pragma unroll
    for (int r = 0; r < 4; ++r)
        out[(size_t)(n0 + ty + r*8) * Kd + k0 + tx] = f2bf(tile[tx][ty + r*8]);
}

// ---------------------------------------------------------------------------
// bf16 MFMA GEMM: C[M,N] fp32 = A[M,K] * BT[Nr,K]^T, write guard col<N.
// 128x128 tile, BK=32, 4 waves each 64x64. Register staging (NO
// global_load_lds — round-2: g2lds diverged on steady-state launches).
// LDS k-chunk XOR swizzle (phys_chunk = chunk ^ (row&3)): kills the 4-way
// quarter-wave bank conflicts of the naive [row][32] layout (round-4 PMC:
// 2.1e7 conflict-cycles ≈ 35 µs/dispatch). Row bases are multiples of 4, so
// read swizzle folds to the constant (quad ^ (lr&3)).
// ---------------------------------------------------------------------------
__global__ __launch_bounds__(256)
void gemm_bf16_mfma(const ushort* __restrict__ A, const ushort* __restrict__ BT,
                    float* __restrict__ C, int Kd, int N, int ldc)
{
    __shared__ ushort As[128*32];   // 8 KB
    __shared__ ushort Bs[128*32];   // 8 KB
    int tid = threadIdx.x, lane = tid & 63;
    int lr = lane & 15, quad = lane >> 4;
    int wave = tid >> 6;
    int wr = (wave >> 1) * 64, wc = (wave & 1) * 64;
    int m0 = blockIdx.y * 128, n0 = blockIdx.x * 128;

    f32x4 acc[4][4] = {};

    const ushort* ga0 = A  + (size_t)(m0 + (tid >> 2)) * Kd + (tid & 3) * 8;
    const ushort* ga1 = ga0 + (size_t)64 * Kd;
    const ushort* gb0 = BT + (size_t)(n0 + (tid >> 2)) * Kd + (tid & 3) * 8;
    const ushort* gb1 = gb0 + (size_t)64 * Kd;
    int srow = tid >> 2;
    int scol = (((tid & 3) ^ (srow & 3)) * 8);     // write-side swizzle
    ushort* la0 = As + srow * 32 + scol;
    ushort* la1 = la0 + 2048;
    ushort* lb0 = Bs + srow * 32 + scol;
    ushort* lb1 = lb0 + 2048;
    int rcol = ((quad ^ (lr & 3)) * 8);            // read-side swizzle

    for (int k0 = 0; k0 < Kd; k0 += 32) {
        u16x8 va0 = *reinterpret_cast<const u16x8*>(ga0);
        u16x8 va1 = *reinterpret_cast<const u16x8*>(ga1);
        u16x8 vb0 = *reinterpret_cast<const u16x8*>(gb0);
        u16x8 vb1 = *reinterpret_cast<const u16x8*>(gb1);
        ga0 += 32; ga1 += 32; gb0 += 32; gb1 += 32;
        __syncthreads();               // prev iteration's LDS reads complete
        *reinterpret_cast<u16x8*>(la0) = va0;
        *reinterpret_cast<u16x8*>(la1) = va1;
        *reinterpret_cast<u16x8*>(lb0) = vb0;
        *reinterpret_cast<u16x8*>(lb1) = vb1;
        __syncthreads();               // staging visible to all waves
        bf16x8 af[4], bf[4];
        #pragma unroll
        for (int i = 0; i < 4; ++i) {
            af[i] = *reinterpret_cast<const bf16x8*>(As + (wr + i*16 + lr) * 32 + rcol);
            bf[i] = *reinterpret_cast<const bf16x8*>(Bs + (wc + i*16 + lr) * 32 + rcol);
        }
        #pragma unroll
        for (int i = 0; i < 4; ++i)
            #pragma unroll
            for (int j = 0; j < 4; ++j)
                acc[i][j] = __builtin_amdgcn_mfma_f32_16x16x32_bf16(
                                af[i], bf[j], acc[i][j], 0, 0, 0);
    }

    #pragma unroll
    for (int i = 0; i < 4; ++i)
        #pragma unroll
        for (int j = 0; j < 4; ++j)
            #pragma unroll
            for (int r = 0; r < 4; ++r) {
                int row = m0 + wr + i*16 + quad*4 + r;      // m89-verified C/D map
                int col = n0 + wc + j*16 + lr;
                if (col < N)
                    C[(size_t)row * ldc + col] = acc[i][j][r];
            }
}

// ---------------------------------------------------------------------------
// Fused spectral+skip MFMA GEMM, gated-SiLU epilogue, bf16 output.
// Tile 128(M) x 64(y-cols); two B-tiles (val,gate); two K-phases.
// Same register staging + XOR swizzle as gemm_bf16_mfma.
// ---------------------------------------------------------------------------
__global__ __launch_bounds__(256)
void gemm2_mfma(const ushort* __restrict__ Sm, const ushort* __restrict__ Xb,
                const ushort* __restrict__ WsV, const ushort* __restrict__ WsG,
                const ushort* __restrict__ WiV, const ushort* __restrict__ WiG,
                ushort* __restrict__ yact)
{
    __shared__ ushort As[128*32];   // 8 KB
    __shared__ ushort Bv[64*32];    // 4 KB
    __shared__ ushort Bg[64*32];    // 4 KB
    int tid = threadIdx.x, lane = tid & 63;
    int lr = lane & 15, quad = lane >> 4;
    int wave = tid >> 6;
    int wr = (wave >> 1) * 64, wc = (wave & 1) * 32;
    int m0 = blockIdx.y * 128, n0 = blockIdx.x * 64;

    f32x4 av[4][2] = {}, ag[4][2] = {};

    int srow = tid >> 2;
    int scol = (((tid & 3) ^ (srow & 3)) * 8);
    int rcol = ((quad ^ (lr & 3)) * 8);

    #pragma unroll 1
    for (int phase = 0; phase < 2; ++phase) {
        const ushort* Ap  = phase ? Xb  : Sm;
        const ushort* Bvp = phase ? WiV : WsV;
        const ushort* Bgp = phase ? WiG : WsG;
        int Kd = phase ? 768 : 1536;

        const ushort* ga0 = Ap  + (size_t)(m0 + srow) * Kd + (tid & 3) * 8;
        const ushort* ga1 = ga0 + (size_t)64 * Kd;
        const ushort* gv  = Bvp + (size_t)(n0 + srow) * Kd + (tid & 3) * 8;
        const ushort* gg  = Bgp + (size_t)(n0 + srow) * Kd + (tid & 3) * 8;
        ushort* la0 = As + srow * 32 + scol;
        ushort* la1 = la0 + 2048;
        ushort* lv  = Bv + srow * 32 + scol;
        ushort* lg  = Bg + srow * 32 + scol;

        for (int k0 = 0; k0 < Kd; k0 += 32) {
            u16x8 va0 = *reinterpret_cast<const u16x8*>(ga0);
            u16x8 va1 = *reinterpret_cast<const u16x8*>(ga1);
            u16x8 vv  = *reinterpret_cast<const u16x8*>(gv);
            u16x8 vg  = *reinterpret_cast<const u16x8*>(gg);
            ga0 += 32; ga1 += 32; gv += 32; gg += 32;
            __syncthreads();
            *reinterpret_cast<u16x8*>(la0) = va0;
            *reinterpret_cast<u16x8*>(la1) = va1;
            *reinterpret_cast<u16x8*>(lv)  = vv;
            *reinterpret_cast<u16x8*>(lg)  = vg;
            __syncthreads();
            bf16x8 af[4], bvf[2], bgf[2];
            #pragma unroll
            for (int i = 0; i < 4; ++i)
                af[i] = *reinterpret_cast<const bf16x8*>(As + (wr + i*16 + lr) * 32 + rcol);
            #pragma unroll
            for (int j = 0; j < 2; ++j) {
                bvf[j] = *reinterpret_cast<const bf16x8*>(Bv + (wc + j*16 + lr) * 32 + rcol);
                bgf[j] = *reinterpret_cast<const bf16x8*>(Bg + (wc + j*16 + lr) * 32 + rcol);
            }
            #pragma unroll
            for (int i = 0; i < 4; ++i)
                #pragma unroll
                for (int j = 0; j < 2; ++j) {
                    av[i][j] = __builtin_amdgcn_mfma_f32_16x16x32_bf16(
                                   af[i], bvf[j], av[i][j], 0, 0, 0);
                    ag[i][j] = __builtin_amdgcn_mfma_f32_16x16x32_bf16(
                                   af[i], bgf[j], ag[i][j], 0, 0, 0);
                }
        }
    }

    #pragma unroll
    for (int i = 0; i < 4; ++i)
        #pragma unroll
        for (int j = 0; j < 2; ++j)
            #pragma unroll
            for (int r = 0; r < 4; ++r) {
                int row = m0 + wr + i*16 + quad*4 + r;
                int col = n0 + wc + j*16 + lr;
                float v = av[i][j][r], g = ag[i][j][r];
                float y = v * (g / (1.f + __expf(-g)));
                yact[(size_t)row * NACT + col] = f2bf(y);
            }
}

// ---------------------------------------------------------------------------
// Token-local: conv(CK=4)+SiLU+RMSNorm(H)+phase -> pw, re, im
// Hot 192-thread path uses hw transcendentals (__expf/__sinf/__cosf,
// tanh_fast); 12-thread p_w path keeps libm expf (error-critical).
// ---------------------------------------------------------------------------
__global__ __launch_bounds__(256)
void token_kernel(const float* __restrict__ zmem, const float* __restrict__ conv_w,
                  const float* __restrict__ rms_scale, const float* __restrict__ theta_raw,
                  const float* __restrict__ dslopes, const float* __restrict__ sscale,
                  const float* __restrict__ tscale,
                  float* __restrict__ pw, float* __restrict__ re, float* __restrict__ im)
{
    int t = blockIdx.x;
    int b = t >> 11;
    int l = t & (L_ - 1);
    int tid = threadIdx.x;
    int h = tid & 63, kg = tid >> 6;

    __shared__ float s_pw[K_];

    if (tid < K_) {
        float acc = 0.f;
        #pragma unroll
        for (int j = 0; j < CK_; ++j) {
            int ll = l - (CK_ - 1) + j;
            if (ll >= 0)
                acc += zmem[(size_t)(b*L_ + ll)*DMK + DIM_MEM_ + tid]
                     * conv_w[j*DMK + DIM_MEM_ + tid];
        }
        float s  = acc / (1.f + expf(-acc));
        float lp = sscale[tid] * s;
        lp = fminf(10.f, fmaxf(-10.f, lp));
        float slope = log1pf(expf(dslopes[tid]));
        s_pw[tid] = expf(lp - slope * (float)(L_ - 1 - l));
    }

    float kv[3];
    #pragma unroll
    for (int q = 0; q < 3; ++q) {
        int kk = kg + q*4;
        int c = kk*H_ + h;
        float acc = 0.f;
        #pragma unroll
        for (int j = 0; j < CK_; ++j) {
            int ll = l - (CK_ - 1) + j;
            if (ll >= 0)
                acc += zmem[(size_t)(b*L_ + ll)*DMK + c] * conv_w[j*DMK + c];
        }
        kv[q] = acc / (1.f + __expf(-acc));          // silu (hw exp)
    }
    __syncthreads();

    #pragma unroll
    for (int q = 0; q < 3; ++q) {
        int kk = kg + q*4;
        float v = kv[q];
        float ss = v * v;
        #pragma unroll
        for (int off = 32; off > 0; off >>= 1)
            ss += __shfl_xor(ss, off, 64);
        float kn = v * rsqrtf(ss * (1.f/64.f) + 1e-6f) * rms_scale[h];
        float th = 0.001f + 2.999f * (1.f / (1.f + __expf(-theta_raw[kk*H_ + h])));
        float phi = tanh_fast(kn * tscale[kk]) * th;
        float kvw = kn * s_pw[kk];
        re[(size_t)t*(K_*H_) + kk*H_ + h] = kvw * __cosf(phi);
        im[(size_t)t*(K_*H_) + kk*H_ + h] = kvw * __sinf(phi);
    }
    if (tid < K_) pw[(size_t)t*K_ + tid] = s_pw[tid];
}

// ---------------------------------------------------------------------------
// Chunked scan pass 1
// ---------------------------------------------------------------------------
__global__ __launch_bounds__(128)
void scan_sums(const float* __restrict__ pw, const float* __restrict__ re,
               const float* __restrict__ im, float* __restrict__ part)
{
    int blk = blockIdx.x;
    int chunk = blk & (NCHUNK - 1);
    int bk = blk >> 4;
    int k = bk % K_;
    int b = bk / K_;
    int tid = threadIdx.x;
    int h = tid & 63;
    const float* __restrict__ src = (tid >> 6) ? im : re;
    int l0 = chunk * CHLEN;

    size_t base  = ((size_t)(b*L_ + l0))*(K_*H_) + k*H_ + h;
    size_t dbase = ((size_t)(b*L_ + l0))*K_ + k;
    float s = 0.f, ds = 0.f;
    for (int i0 = 0; i0 < CHLEN; i0 += 8) {
        float v[8], d[8];
        #pragma unroll
        for (int j = 0; j < 8; ++j) {
            v[j] = src[base + (size_t)(i0 + j)*(K_*H_)];
            d[j] = pw [dbase + (size_t)(i0 + j)*K_];
        }
        #pragma unroll
        for (int j = 0; j < 8; ++j) { s += v[j]; ds += d[j]; }
    }
    size_t pb = ((size_t)bk * NCHUNK + chunk) * PSTRIDE;
    part[pb + tid] = s;
    if (tid == 0) part[pb + 128] = ds;
}

// ---------------------------------------------------------------------------
// Chunked scan pass 2: emit summary directly as bf16.
// ---------------------------------------------------------------------------
__global__ __launch_bounds__(128)
void scan_final(const float* __restrict__ pw, const float* __restrict__ re,
                const float* __restrict__ im, const float* __restrict__ part,
                ushort* __restrict__ summary)
{
    int blk = blockIdx.x;
    int chunk = blk & (NCHUNK - 1);
    int bk = blk >> 4;
    int k = bk % K_;
    int b = bk / K_;
    int tid = threadIdx.x;
    int h = tid & 63;
    int pi = tid >> 6;
    const float* __restrict__ src = pi ? im : re;
    int l0 = chunk * CHLEN;

    float acc = 0.f, dacc = 0.f;
    size_t pb0 = (size_t)bk * NCHUNK * PSTRIDE;
    for (int cn = 0; cn < chunk; ++cn) {
        acc  += part[pb0 + (size_t)cn*PSTRIDE + tid];
        dacc += part[pb0 + (size_t)cn*PSTRIDE + 128];
    }

    size_t base  = ((size_t)(b*L_ + l0))*(K_*H_) + k*H_ + h;
    size_t dbase = ((size_t)(b*L_ + l0))*K_ + k;
    int outch = 2*(k*H_ + h) + pi;
    for (int i0 = 0; i0 < CHLEN; i0 += 8) {
        float v[8], d[8];
        #pragma unroll
        for (int j = 0; j < 8; ++j) {
            v[j] = src[base + (size_t)(i0 + j)*(K_*H_)];
            d[j] = pw [dbase + (size_t)(i0 + j)*K_];
        }
        #pragma unroll
        for (int j = 0; j < 8; ++j) {
            acc += v[j]; dacc += d[j];
            float inv = 1.f / fmaxf(dacc, 1e-4f);
            summary[((size_t)(b*L_ + l0 + i0 + j))*NSUM + outch] = f2bf(acc * inv);
        }
    }
}

// ---------------------------------------------------------------------------
extern "C" void kernel_launch(void* const* d_in, const int* in_sizes, int n_in,
                              void* d_out, int out_size, void* d_ws, size_t ws_size,
                              hipStream_t stream)
{
    const float* x         = (const float*)d_in[0];
    const float* W_in      = (const float*)d_in[1];
    const float* conv_w    = (const float*)d_in[2];
    const float* rms_scale = (const float*)d_in[3];
    const float* theta_raw = (const float*)d_in[4];
    const float* dslopes   = (const float*)d_in[5];
    const float* sscale    = (const float*)d_in[6];
    const float* tscale    = (const float*)d_in[7];
    const float* W_sw      = (const float*)d_in[8];
    const float* W_out     = (const float*)d_in[9];
    float* out = (float*)d_out;
    char* ws   = (char*)d_ws;

    // Workspace (byte offsets, all 256-aligned). Peak ~115.4 MB (< proven 127).
    float*  zmem    = (float*) (ws + 0);           // NT*780 f32   = 25,559,040 B
    ushort* summary = (ushort*)(ws + 0);           // alias (zmem dead): 25,165,824 B
    float*  pw      = (float*) (ws + 25559040);    //   393,216 B
    float*  re      = (float*) (ws + 25952256);    // 25,165,824 B
    float*  im      = (float*) (ws + 51118080);    // 25,165,824 B
    ushort* yact    = (ushort*)(ws + 25952256);    // alias re+im (dead): 37,748,736 B
    float*  part    = (float*) (ws + 76283904);    //   405,504 B
    ushort* xb      = (ushort*)(ws + 76689408);    // 12,582,912 B
    ushort* WiV     = (ushort*)(ws + 89272320);    //  3,538,944 B  [2304][768]
    ushort* WiG     = (ushort*)(ws + 92811264);    //  3,538,944 B
    ushort* WsV     = (ushort*)(ws + 96350208);    //  7,077,888 B  [2304][1536]
    ushort* WsG     = (ushort*)(ws + 103428096);   //  7,077,888 B
    ushort* WoT     = (ushort*)(ws + 110505984);   //  3,538,944 B  [768][2304]
    ushort* WimT    = (ushort*)(ws + 114044928);   //  1,376,256 B  [896][768] (pad)

    // ---- merged prep job table ----
    PrepJobs J;
    J.W[0]=W_in;  J.out[0]=WiV;  J.ldw[0]=5388; J.Kd[0]=768;  J.colbase[0]=780; J.remap[0]=1; J.ntx[0]=72;
    J.W[1]=W_in;  J.out[1]=WiG;  J.ldw[1]=5388; J.Kd[1]=768;  J.colbase[1]=972; J.remap[1]=1; J.ntx[1]=72;
    J.W[2]=W_sw;  J.out[2]=WsV;  J.ldw[2]=4608; J.Kd[2]=1536; J.colbase[2]=0;   J.remap[2]=1; J.ntx[2]=72;
    J.W[3]=W_sw;  J.out[3]=WsG;  J.ldw[3]=4608; J.Kd[3]=1536; J.colbase[3]=192; J.remap[3]=1; J.ntx[3]=72;
    J.W[4]=W_out; J.out[4]=WoT;  J.ldw[4]=768;  J.Kd[4]=2304; J.colbase[4]=0;   J.remap[4]=0; J.ntx[4]=24;
    J.W[5]=W_in;  J.out[5]=WimT; J.ldw[5]=5388; J.Kd[5]=768;  J.colbase[5]=0;   J.remap[5]=0; J.ntx[5]=28;
    int tiles[6] = {72*24, 72*24, 72*48, 72*48, 24*72, 28*24};
    J.start[0] = 0;
    for (int j = 0; j < 6; ++j) J.start[j+1] = J.start[j] + tiles[j];
    J.cast_in = x; J.cast_out = xb; J.n4 = NT*D_/4;
    int nblk = J.start[6] + (J.n4 + 255)/256;

    dim3 blk(256);
    // 0) all preps in one launch
    prep_all<<<dim3(nblk), blk, 0, stream>>>(J);
    // 1) z_mem = x @ W_in[:, :780]  (bf16 MFMA, col-guarded at 780)
    gemm_bf16_mfma<<<dim3(7, 64), blk, 0, stream>>>(xb, WimT, zmem, 768, 780, 780);
    // 2) conv + silu + rmsnorm + phase
    token_kernel<<<dim3(NT), blk, 0, stream>>>(zmem, conv_w, rms_scale, theta_raw,
                                               dslopes, sscale, tscale, pw, re, im);
    // 3) chunked cumsum -> summary (bf16)
    scan_sums <<<dim3(B_*K_*NCHUNK), dim3(128), 0, stream>>>(pw, re, im, part);
    scan_final<<<dim3(B_*K_*NCHUNK), dim3(128), 0, stream>>>(pw, re, im, part, summary);
    // 4) fused spectral+skip MFMA GEMM with gated-SiLU epilogue -> yact (bf16)
    gemm2_mfma<<<dim3(NACT/64, NT/128), blk, 0, stream>>>(summary, xb,
                                                          WsV, WsG, WiV, WiG, yact);
    // 5) out = yact @ W_out  (MFMA)
    gemm_bf16_mfma<<<dim3(6, 64), blk, 0, stream>>>(yact, WoT, out, 2304, 768, 768);
}

// Round 7
// 440.609 us; speedup vs baseline: 6.0843x; 1.1330x over previous
//
#include <hip/hip_runtime.h>
#include <hip/hip_bf16.h>

// Problem constants (B,L,D)=(4,2048,768), K=12, M=1, CK=4, H=64
#define B_       4
#define L_       2048
#define D_       768
#define K_       12
#define H_       64
#define CK_      4
#define DIM_MEM_ 768
#define DMK      780        // DIM_MEM + K
#define NT       (B_*L_)    // 8192 tokens
#define NSUM     1536       // 2*K*H  (summary width)
#define NACT     2304       // K*192  (y_act width)
#define NCHUNK   16
#define CHLEN    (L_/NCHUNK)  // 128
#define PSTRIDE  132

typedef __attribute__((ext_vector_type(8))) short          bf16x8;
typedef __attribute__((ext_vector_type(8))) unsigned short u16x8;
typedef __attribute__((ext_vector_type(4))) float          f32x4;

__device__ __forceinline__ ushort f2bf(float v) {
    __hip_bfloat16 h = __float2bfloat16(v);
    return *reinterpret_cast<ushort*>(&h);
}
// fast tanh via hw exp; safe for any x
__device__ __forceinline__ float tanh_fast(float x) {
    float t = __expf(-2.f * fabsf(x));
    float r = (1.f - t) / (1.f + t);
    return copysignf(r, x);
}

// ---------------------------------------------------------------------------
// Merged prep: 6 transpose-cast jobs (32x32 LDS tiles) + x->bf16 cast.
// ---------------------------------------------------------------------------
struct PrepJobs {
    const float* W[6];
    ushort*      out[6];
    int ldw[6], Kd[6], colbase[6], remap[6], ntx[6];
    int start[7];
    const float* cast_in;
    ushort*      cast_out;
    int n4;
};

__global__ __launch_bounds__(256)
void prep_all(PrepJobs J)
{
    int blk = blockIdx.x;
    if (blk >= J.start[6]) {                       // cast job
        int i = (blk - J.start[6]) * 256 + threadIdx.x;
        if (i < J.n4) {
            float4 v = reinterpret_cast<const float4*>(J.cast_in)[i];
            ushort4 o;
            o.x = f2bf(v.x); o.y = f2bf(v.y); o.z = f2bf(v.z); o.w = f2bf(v.w);
            reinterpret_cast<ushort4*>(J.cast_out)[i] = o;
        }
        return;
    }
    int j = 0;
    while (blk >= J.start[j + 1]) ++j;
    int rel = blk - J.start[j];
    int ntx = J.ntx[j];
    int n0 = (rel % ntx) * 32, k0 = (rel / ntx) * 32;
    const float* W = J.W[j];
    int ldw = J.ldw[j], Kd = J.Kd[j], colbase = J.colbase[j], remap = J.remap[j];
    ushort* out = J.out[j];

    __shared__ float tile[32][33];
    int tx = threadIdx.x & 31, ty = threadIdx.x >> 5;
    int n = n0 + tx;
    int c = colbase + (remap ? (n/192)*384 + (n%192) : n);
    #pragma unroll
    for (int r = 0; r < 4; ++r)
        tile[ty + r*8][tx] = W[(size_t)(k0 + ty + r*8) * ldw + c];
    __syncthreads();
    #pragma unroll
    for (int r = 0; r < 4; ++r)
        out[(size_t)(n0 + ty + r*8) * Kd + k0 + tx] = f2bf(tile[tx][ty + r*8]);
}

// ---------------------------------------------------------------------------
// bf16 MFMA GEMM: C[M,N] fp32 = A[M,K] * BT[Nr,K]^T, write guard col<N.
// 128x128 tile, BK=64, 4 waves each 64x64. PROVEN sync discipline only
// (r3-r5: loads -> barrier -> ds_write -> barrier -> mfma; r2/r6 variants
// that carry staging across barriers diverged on steady-state launches).
// BK=64 halves barrier pairs: 32 MFMA per 2 barriers. LDS 32 KB single-buf.
// k-chunk XOR swizzle: phys_chunk = chunk ^ (row&7).
// ---------------------------------------------------------------------------
__global__ __launch_bounds__(256)
void gemm_bf16_mfma(const ushort* __restrict__ A, const ushort* __restrict__ BT,
                    float* __restrict__ C, int Kd, int N, int ldc)
{
    __shared__ ushort As[128*64];   // 16 KB
    __shared__ ushort Bs[128*64];   // 16 KB
    int tid = threadIdx.x, lane = tid & 63;
    int lr = lane & 15, quad = lane >> 4;
    int wave = tid >> 6;
    int wr = (wave >> 1) * 64, wc = (wave & 1) * 64;
    int m0 = blockIdx.y * 128, n0 = blockIdx.x * 128;

    f32x4 acc[4][4] = {};

    int srow = tid >> 3;                       // 0..31
    int tc   = tid & 7;                        // logical k-chunk (8B*2=16B)
    const ushort* gA = A  + (size_t)(m0 + srow) * Kd + tc * 8;
    const ushort* gB = BT + (size_t)(n0 + srow) * Kd + tc * 8;
    int woff = srow * 64 + ((tc ^ (srow & 7)) * 8);
    int rx = lr & 7;

    for (int k0 = 0; k0 < Kd; k0 += 64) {
        u16x8 a[4], b[4];
        #pragma unroll
        for (int p = 0; p < 4; ++p) {
            a[p] = *reinterpret_cast<const u16x8*>(gA + (size_t)(32*p) * Kd);
            b[p] = *reinterpret_cast<const u16x8*>(gB + (size_t)(32*p) * Kd);
        }
        gA += 64; gB += 64;
        __syncthreads();               // prev iteration's LDS reads complete
        #pragma unroll
        for (int p = 0; p < 4; ++p) {
            *reinterpret_cast<u16x8*>(As + woff + p*2048) = a[p];
            *reinterpret_cast<u16x8*>(Bs + woff + p*2048) = b[p];
        }
        __syncthreads();               // staging visible to all waves
        #pragma unroll
        for (int ks = 0; ks < 2; ++ks) {
            bf16x8 af[4], bf[4];
            #pragma unroll
            for (int i = 0; i < 4; ++i) {
                int ca = ((ks*4 + quad) ^ rx) * 8;
                af[i] = *reinterpret_cast<const bf16x8*>(As + (wr + i*16 + lr) * 64 + ca);
                bf[i] = *reinterpret_cast<const bf16x8*>(Bs + (wc + i*16 + lr) * 64 + ca);
            }
            #pragma unroll
            for (int i = 0; i < 4; ++i)
                #pragma unroll
                for (int j = 0; j < 4; ++j)
                    acc[i][j] = __builtin_amdgcn_mfma_f32_16x16x32_bf16(
                                    af[i], bf[j], acc[i][j], 0, 0, 0);
        }
    }

    #pragma unroll
    for (int i = 0; i < 4; ++i)
        #pragma unroll
        for (int j = 0; j < 4; ++j)
            #pragma unroll
            for (int r = 0; r < 4; ++r) {
                int row = m0 + wr + i*16 + quad*4 + r;      // m89-verified C/D map
                int col = n0 + wc + j*16 + lr;
                if (col < N)
                    C[(size_t)row * ldc + col] = acc[i][j][r];
            }
}

// ---------------------------------------------------------------------------
// Fused spectral+skip MFMA GEMM, gated-SiLU epilogue, bf16 output.
// Tile 128(M) x 64(y-cols); two B-tiles (val,gate); two K-phases
// (phase0: A=summary K=1536, B=Wsw; phase1: A=x K=768, B=W_in).
// Same BK=64 2-barrier structure as gemm_bf16_mfma.
// ---------------------------------------------------------------------------
__global__ __launch_bounds__(256)
void gemm2_mfma(const ushort* __restrict__ Sm, const ushort* __restrict__ Xb,
                const ushort* __restrict__ WsV, const ushort* __restrict__ WsG,
                const ushort* __restrict__ WiV, const ushort* __restrict__ WiG,
                ushort* __restrict__ yact)
{
    __shared__ ushort As[128*64];   // 16 KB
    __shared__ ushort Bv[64*64];    // 8 KB
    __shared__ ushort Bg[64*64];    // 8 KB
    int tid = threadIdx.x, lane = tid & 63;
    int lr = lane & 15, quad = lane >> 4;
    int wave = tid >> 6;
    int wr = (wave >> 1) * 64, wc = (wave & 1) * 32;
    int m0 = blockIdx.y * 128, n0 = blockIdx.x * 64;

    f32x4 av[4][2] = {}, ag[4][2] = {};

    int srow = tid >> 3;
    int tc   = tid & 7;
    int woff = srow * 64 + ((tc ^ (srow & 7)) * 8);
    int rx = lr & 7;

    #pragma unroll 1
    for (int phase = 0; phase < 2; ++phase) {
        const ushort* Ap  = phase ? Xb  : Sm;
        const ushort* Bvp = phase ? WiV : WsV;
        const ushort* Bgp = phase ? WiG : WsG;
        int Kd = phase ? 768 : 1536;

        const ushort* gA = Ap  + (size_t)(m0 + srow) * Kd + tc * 8;
        const ushort* gv = Bvp + (size_t)(n0 + srow) * Kd + tc * 8;
        const ushort* gg = Bgp + (size_t)(n0 + srow) * Kd + tc * 8;

        for (int k0 = 0; k0 < Kd; k0 += 64) {
            u16x8 a[4], v2[2], g2[2];
            #pragma unroll
            for (int p = 0; p < 4; ++p)
                a[p] = *reinterpret_cast<const u16x8*>(gA + (size_t)(32*p) * Kd);
            #pragma unroll
            for (int p = 0; p < 2; ++p) {
                v2[p] = *reinterpret_cast<const u16x8*>(gv + (size_t)(32*p) * Kd);
                g2[p] = *reinterpret_cast<const u16x8*>(gg + (size_t)(32*p) * Kd);
            }
            gA += 64; gv += 64; gg += 64;
            __syncthreads();
            #pragma unroll
            for (int p = 0; p < 4; ++p)
                *reinterpret_cast<u16x8*>(As + woff + p*2048) = a[p];
            #pragma unroll
            for (int p = 0; p < 2; ++p) {
                *reinterpret_cast<u16x8*>(Bv + woff + p*2048) = v2[p];
                *reinterpret_cast<u16x8*>(Bg + woff + p*2048) = g2[p];
            }
            __syncthreads();
            #pragma unroll
            for (int ks = 0; ks < 2; ++ks) {
                bf16x8 af[4], bvf[2], bgf[2];
                #pragma unroll
                for (int i = 0; i < 4; ++i) {
                    int ca = ((ks*4 + quad) ^ rx) * 8;
                    af[i] = *reinterpret_cast<const bf16x8*>(As + (wr + i*16 + lr) * 64 + ca);
                }
                #pragma unroll
                for (int j = 0; j < 2; ++j) {
                    int ca = ((ks*4 + quad) ^ rx) * 8;
                    bvf[j] = *reinterpret_cast<const bf16x8*>(Bv + (wc + j*16 + lr) * 64 + ca);
                    bgf[j] = *reinterpret_cast<const bf16x8*>(Bg + (wc + j*16 + lr) * 64 + ca);
                }
                #pragma unroll
                for (int i = 0; i < 4; ++i)
                    #pragma unroll
                    for (int j = 0; j < 2; ++j) {
                        av[i][j] = __builtin_amdgcn_mfma_f32_16x16x32_bf16(
                                       af[i], bvf[j], av[i][j], 0, 0, 0);
                        ag[i][j] = __builtin_amdgcn_mfma_f32_16x16x32_bf16(
                                       af[i], bgf[j], ag[i][j], 0, 0, 0);
                    }
            }
        }
    }

    #pragma unroll
    for (int i = 0; i < 4; ++i)
        #pragma unroll
        for (int j = 0; j < 2; ++j)
            #pragma unroll
            for (int r = 0; r < 4; ++r) {
                int row = m0 + wr + i*16 + quad*4 + r;
                int col = n0 + wc + j*16 + lr;
                float v = av[i][j][r], g = ag[i][j][r];
                float y = v * (g / (1.f + __expf(-g)));
                yact[(size_t)row * NACT + col] = f2bf(y);
            }
}

// ---------------------------------------------------------------------------
// Token-local: conv(CK=4)+SiLU+RMSNorm(H)+phase -> pw, re, im
// ---------------------------------------------------------------------------
__global__ __launch_bounds__(256)
void token_kernel(const float* __restrict__ zmem, const float* __restrict__ conv_w,
                  const float* __restrict__ rms_scale, const float* __restrict__ theta_raw,
                  const float* __restrict__ dslopes, const float* __restrict__ sscale,
                  const float* __restrict__ tscale,
                  float* __restrict__ pw, float* __restrict__ re, float* __restrict__ im)
{
    int t = blockIdx.x;
    int b = t >> 11;
    int l = t & (L_ - 1);
    int tid = threadIdx.x;
    int h = tid & 63, kg = tid >> 6;

    __shared__ float s_pw[K_];

    if (tid < K_) {
        float acc = 0.f;
        #pragma unroll
        for (int j = 0; j < CK_; ++j) {
            int ll = l - (CK_ - 1) + j;
            if (ll >= 0)
                acc += zmem[(size_t)(b*L_ + ll)*DMK + DIM_MEM_ + tid]
                     * conv_w[j*DMK + DIM_MEM_ + tid];
        }
        float s  = acc / (1.f + expf(-acc));
        float lp = sscale[tid] * s;
        lp = fminf(10.f, fmaxf(-10.f, lp));
        float slope = log1pf(expf(dslopes[tid]));
        s_pw[tid] = expf(lp - slope * (float)(L_ - 1 - l));
    }

    float kv[3];
    #pragma unroll
    for (int q = 0; q < 3; ++q) {
        int kk = kg + q*4;
        int c = kk*H_ + h;
        float acc = 0.f;
        #pragma unroll
        for (int j = 0; j < CK_; ++j) {
            int ll = l - (CK_ - 1) + j;
            if (ll >= 0)
                acc += zmem[(size_t)(b*L_ + ll)*DMK + c] * conv_w[j*DMK + c];
        }
        kv[q] = acc / (1.f + __expf(-acc));          // silu (hw exp)
    }
    __syncthreads();

    #pragma unroll
    for (int q = 0; q < 3; ++q) {
        int kk = kg + q*4;
        float v = kv[q];
        float ss = v * v;
        #pragma unroll
        for (int off = 32; off > 0; off >>= 1)
            ss += __shfl_xor(ss, off, 64);
        float kn = v * rsqrtf(ss * (1.f/64.f) + 1e-6f) * rms_scale[h];
        float th = 0.001f + 2.999f * (1.f / (1.f + __expf(-theta_raw[kk*H_ + h])));
        float phi = tanh_fast(kn * tscale[kk]) * th;
        float kvw = kn * s_pw[kk];
        re[(size_t)t*(K_*H_) + kk*H_ + h] = kvw * __cosf(phi);
        im[(size_t)t*(K_*H_) + kk*H_ + h] = kvw * __sinf(phi);
    }
    if (tid < K_) pw[(size_t)t*K_ + tid] = s_pw[tid];
}

// ---------------------------------------------------------------------------
// Chunked scan pass 1
// ---------------------------------------------------------------------------
__global__ __launch_bounds__(128)
void scan_sums(const float* __restrict__ pw, const float* __restrict__ re,
               const float* __restrict__ im, float* __restrict__ part)
{
    int blk = blockIdx.x;
    int chunk = blk & (NCHUNK - 1);
    int bk = blk >> 4;
    int k = bk % K_;
    int b = bk / K_;
    int tid = threadIdx.x;
    int h = tid & 63;
    const float* __restrict__ src = (tid >> 6) ? im : re;
    int l0 = chunk * CHLEN;

    size_t base  = ((size_t)(b*L_ + l0))*(K_*H_) + k*H_ + h;
    size_t dbase = ((size_t)(b*L_ + l0))*K_ + k;
    float s = 0.f, ds = 0.f;
    for (int i0 = 0; i0 < CHLEN; i0 += 8) {
        float v[8], d[8];
        #pragma unroll
        for (int j = 0; j < 8; ++j) {
            v[j] = src[base + (size_t)(i0 + j)*(K_*H_)];
            d[j] = pw [dbase + (size_t)(i0 + j)*K_];
        }
        #pragma unroll
        for (int j = 0; j < 8; ++j) { s += v[j]; ds += d[j]; }
    }
    size_t pb = ((size_t)bk * NCHUNK + chunk) * PSTRIDE;
    part[pb + tid] = s;
    if (tid == 0) part[pb + 128] = ds;
}

// ---------------------------------------------------------------------------
// Chunked scan pass 2: emit summary directly as bf16.
// ---------------------------------------------------------------------------
__global__ __launch_bounds__(128)
void scan_final(const float* __restrict__ pw, const float* __restrict__ re,
                const float* __restrict__ im, const float* __restrict__ part,
                ushort* __restrict__ summary)
{
    int blk = blockIdx.x;
    int chunk = blk & (NCHUNK - 1);
    int bk = blk >> 4;
    int k = bk % K_;
    int b = bk / K_;
    int tid = threadIdx.x;
    int h = tid & 63;
    int pi = tid >> 6;
    const float* __restrict__ src = pi ? im : re;
    int l0 = chunk * CHLEN;

    float acc = 0.f, dacc = 0.f;
    size_t pb0 = (size_t)bk * NCHUNK * PSTRIDE;
    for (int cn = 0; cn < chunk; ++cn) {
        acc  += part[pb0 + (size_t)cn*PSTRIDE + tid];
        dacc += part[pb0 + (size_t)cn*PSTRIDE + 128];
    }

    size_t base  = ((size_t)(b*L_ + l0))*(K_*H_) + k*H_ + h;
    size_t dbase = ((size_t)(b*L_ + l0))*K_ + k;
    int outch = 2*(k*H_ + h) + pi;
    for (int i0 = 0; i0 < CHLEN; i0 += 8) {
        float v[8], d[8];
        #pragma unroll
        for (int j = 0; j < 8; ++j) {
            v[j] = src[base + (size_t)(i0 + j)*(K_*H_)];
            d[j] = pw [dbase + (size_t)(i0 + j)*K_];
        }
        #pragma unroll
        for (int j = 0; j < 8; ++j) {
            acc += v[j]; dacc += d[j];
            float inv = 1.f / fmaxf(dacc, 1e-4f);
            summary[((size_t)(b*L_ + l0 + i0 + j))*NSUM + outch] = f2bf(acc * inv);
        }
    }
}

// ---------------------------------------------------------------------------
extern "C" void kernel_launch(void* const* d_in, const int* in_sizes, int n_in,
                              void* d_out, int out_size, void* d_ws, size_t ws_size,
                              hipStream_t stream)
{
    const float* x         = (const float*)d_in[0];
    const float* W_in      = (const float*)d_in[1];
    const float* conv_w    = (const float*)d_in[2];
    const float* rms_scale = (const float*)d_in[3];
    const float* theta_raw = (const float*)d_in[4];
    const float* dslopes   = (const float*)d_in[5];
    const float* sscale    = (const float*)d_in[6];
    const float* tscale    = (const float*)d_in[7];
    const float* W_sw      = (const float*)d_in[8];
    const float* W_out     = (const float*)d_in[9];
    float* out = (float*)d_out;
    char* ws   = (char*)d_ws;

    // Workspace (byte offsets, all 256-aligned). Peak ~115.4 MB (< proven 127).
    float*  zmem    = (float*) (ws + 0);           // NT*780 f32   = 25,559,040 B
    ushort* summary = (ushort*)(ws + 0);           // alias (zmem dead): 25,165,824 B
    float*  pw      = (float*) (ws + 25559040);    //   393,216 B
    float*  re      = (float*) (ws + 25952256);    // 25,165,824 B
    float*  im      = (float*) (ws + 51118080);    // 25,165,824 B
    ushort* yact    = (ushort*)(ws + 25952256);    // alias re+im (dead): 37,748,736 B
    float*  part    = (float*) (ws + 76283904);    //   405,504 B
    ushort* xb      = (ushort*)(ws + 76689408);    // 12,582,912 B
    ushort* WiV     = (ushort*)(ws + 89272320);    //  3,538,944 B  [2304][768]
    ushort* WiG     = (ushort*)(ws + 92811264);    //  3,538,944 B
    ushort* WsV     = (ushort*)(ws + 96350208);    //  7,077,888 B  [2304][1536]
    ushort* WsG     = (ushort*)(ws + 103428096);   //  7,077,888 B
    ushort* WoT     = (ushort*)(ws + 110505984);   //  3,538,944 B  [768][2304]
    ushort* WimT    = (ushort*)(ws + 114044928);   //  1,376,256 B  [896][768] (pad)

    // ---- merged prep job table ----
    PrepJobs J;
    J.W[0]=W_in;  J.out[0]=WiV;  J.ldw[0]=5388; J.Kd[0]=768;  J.colbase[0]=780; J.remap[0]=1; J.ntx[0]=72;
    J.W[1]=W_in;  J.out[1]=WiG;  J.ldw[1]=5388; J.Kd[1]=768;  J.colbase[1]=972; J.remap[1]=1; J.ntx[1]=72;
    J.W[2]=W_sw;  J.out[2]=WsV;  J.ldw[2]=4608; J.Kd[2]=1536; J.colbase[2]=0;   J.remap[2]=1; J.ntx[2]=72;
    J.W[3]=W_sw;  J.out[3]=WsG;  J.ldw[3]=4608; J.Kd[3]=1536; J.colbase[3]=192; J.remap[3]=1; J.ntx[3]=72;
    J.W[4]=W_out; J.out[4]=WoT;  J.ldw[4]=768;  J.Kd[4]=2304; J.colbase[4]=0;   J.remap[4]=0; J.ntx[4]=24;
    J.W[5]=W_in;  J.out[5]=WimT; J.ldw[5]=5388; J.Kd[5]=768;  J.colbase[5]=0;   J.remap[5]=0; J.ntx[5]=28;
    int tiles[6] = {72*24, 72*24, 72*48, 72*48, 24*72, 28*24};
    J.start[0] = 0;
    for (int j = 0; j < 6; ++j) J.start[j+1] = J.start[j] + tiles[j];
    J.cast_in = x; J.cast_out = xb; J.n4 = NT*D_/4;
    int nblk = J.start[6] + (J.n4 + 255)/256;

    dim3 blk(256);
    // 0) all preps in one launch
    prep_all<<<dim3(nblk), blk, 0, stream>>>(J);
    // 1) z_mem = x @ W_in[:, :780]  (bf16 MFMA, col-guarded at 780)
    gemm_bf16_mfma<<<dim3(7, 64), blk, 0, stream>>>(xb, WimT, zmem, 768, 780, 780);
    // 2) conv + silu + rmsnorm + phase
    token_kernel<<<dim3(NT), blk, 0, stream>>>(zmem, conv_w, rms_scale, theta_raw,
                                               dslopes, sscale, tscale, pw, re, im);
    // 3) chunked cumsum -> summary (bf16)
    scan_sums <<<dim3(B_*K_*NCHUNK), dim3(128), 0, stream>>>(pw, re, im, part);
    scan_final<<<dim3(B_*K_*NCHUNK), dim3(128), 0, stream>>>(pw, re, im, part, summary);
    // 4) fused spectral+skip MFMA GEMM with gated-SiLU epilogue -> yact (bf16)
    gemm2_mfma<<<dim3(NACT/64, NT/128), blk, 0, stream>>>(summary, xb,
                                                          WsV, WsG, WiV, WiG, yact);
    // 5) out = yact @ W_out  (MFMA)
    gemm_bf16_mfma<<<dim3(6, 64), blk, 0, stream>>>(yact, WoT, out, 2304, 768, 768);
}